// Round 10
// baseline (230.480 us; speedup 1.0000x reference)
//
#include <hip/hip_runtime.h>
#include <stdint.h>

typedef unsigned long long u64;
typedef unsigned int u32;

#define CDIM 256
#define NCODES 8192
#define MTOT 16384
#define OUT_ELEMS 4194304   // 16*256*32*32
#define BETA 0.25f

// ws layout (bytes)
#define WS_PACKED 0u            // 16384*8 = 131072
#define WS_ENORM  131072u       // 32768
#define WS_ZSQ    163840u       // 65536
#define WS_COUNTS 229376u       // 32768
#define WS_LOSS   262144u       // 256 (only 4 used)
#define WS_ZSQ4   262400u       // 16384*4*4 = 262144
#define WS_ZB     524544u       // 16384*256*2 = 8388608
#define WS_EB     8913152u      // 8192*256*2 = 4194304
#define WS_TT2    13107456u     // 64*16384*8 = 8388608 (uint2 keys, [tile][m])
#define WS_NEEDED 21496064u

typedef short bf16x8 __attribute__((ext_vector_type(8)));
typedef float f32x4 __attribute__((ext_vector_type(4)));

#define GL2LDS16(g, l) __builtin_amdgcn_global_load_lds(            \
    (const __attribute__((address_space(1))) void*)(g),             \
    (__attribute__((address_space(3))) void*)(l), 16, 0, 0)

__device__ __forceinline__ unsigned short f2bf(float f) {
  u32 u = __float_as_uint(f);
  u32 r = (u + 0x7FFFu + ((u >> 16) & 1u)) >> 16;   // RNE
  return (unsigned short)r;
}

// ---------------- convert: z NCHW->NHWC bf16 + zsq quarters; E->bf16 + enorm ----------------
__global__ void conv_kernel(const float* __restrict__ z, const float* __restrict__ E,
                            unsigned short* __restrict__ zb, unsigned short* __restrict__ eb,
                            float* __restrict__ zsq4, float* __restrict__ enorm) {
  int blk = blockIdx.x;
  int t = threadIdx.x, w = t >> 6, lane = t & 63;
  if (blk < 1024) {
    __shared__ unsigned short tz[64][66];
    __shared__ float part[4][64];
    int b = blk >> 6, rem = blk & 63;
    int ct = rem >> 4, pt = rem & 15;
    int c0 = ct << 6, p0 = pt << 6;
    const float* zp = z + ((size_t)b << 18) + ((size_t)c0 << 10) + p0;
    float sq = 0.f;
    #pragma unroll
    for (int i = 0; i < 16; ++i) {
      int cl = w + (i << 2);
      float v = zp[((size_t)cl << 10) + lane];
      sq = fmaf(v, v, sq);
      tz[cl][lane] = f2bf(v);
    }
    part[w][lane] = sq;
    __syncthreads();
    if (w == 0) {
      float s = ((part[0][lane] + part[1][lane]) + part[2][lane]) + part[3][lane];
      zsq4[(((size_t)b << 10) + p0 + lane) * 4 + ct] = s;
    }
    #pragma unroll
    for (int j = 0; j < 16; ++j) {
      int pl = w + (j << 2);
      zb[(((size_t)b << 10) + p0 + pl) * 256 + c0 + lane] = tz[lane][pl];
    }
  } else {
    int e4 = blk - 1024;                 // 1024 blocks, 8 E-rows each
    size_t base = ((size_t)e4 << 11) + ((size_t)t << 3);
    float4 v0 = *(const float4*)&E[base];
    float4 v1 = *(const float4*)&E[base + 4];
    ushort4 o0 = { f2bf(v0.x), f2bf(v0.y), f2bf(v0.z), f2bf(v0.w) };
    ushort4 o1 = { f2bf(v1.x), f2bf(v1.y), f2bf(v1.z), f2bf(v1.w) };
    *(ushort4*)&eb[base] = o0;
    *(ushort4*)&eb[base + 4] = o1;
    // enorm (order-insensitive: always rounds away against zsq)
    float s = v0.x * v0.x + v0.y * v0.y + v0.z * v0.z + v0.w * v0.w
            + v1.x * v1.x + v1.y * v1.y + v1.z * v1.z + v1.w * v1.w;
    #pragma unroll
    for (int off = 16; off; off >>= 1) s += __shfl_xor(s, off, 32);
    if ((t & 31) == 0) enorm[(e4 << 3) + (t >> 5)] = s;
  }
}

__global__ void zsqfin_kernel(const float* __restrict__ zsq4, float* __restrict__ zsq) {
  int m = blockIdx.x * 256 + threadIdx.x;
  float4 v = *(const float4*)&zsq4[(size_t)m * 4];
  zsq[m] = ((v.x + v.y) + v.z) + v.w;   // ((q0+q1)+q2)+q3, same as passing rounds
}

// ---------------- K1: bf16 MFMA GEMM, r5 geometry (BM=256,BN=128, 256 thr, 4 waves)
// + BK=32 double-buffer T3-minimum 2-phase (stage kt+1 issued BEFORE compute kt),
// 48 KB LDS -> 3 blocks/CU (implicit + explicit overlap). No XCD swizzle (L3-fit regime).
// 4-granule rows: slot = j ^ ((row>>1)&3)  (8-class x 8-lane bank structure, as r5). ----------
__global__ __launch_bounds__(256, 3) void gemm_kernel(
    const unsigned short* __restrict__ zb, const unsigned short* __restrict__ eb,
    uint2* __restrict__ tt2) {
  __shared__ unsigned short As[2][256 * 32];   // 2 x 16 KB
  __shared__ unsigned short Bs[2][128 * 32];   // 2 x 8 KB   (48 KB total)
  const int t = threadIdx.x;
  const int w = t >> 6, lane = t & 63;
  const int r16 = lane & 15, kg = lane >> 4;
  const int m0 = blockIdx.x << 8, n0 = blockIdx.y << 7;

  f32x4 acc[4][8];
  #pragma unroll
  for (int i = 0; i < 4; ++i)
    #pragma unroll
    for (int j = 0; j < 8; ++j) acc[i][j] = (f32x4)0.f;

  // staging: thread t stages granule g=i*256+t -> (row=g>>2, slot=g&3);
  // source granule j = (t&3) ^ ((t>>3)&3)   [= slot ^ ((row>>1)&3)]
  const int jsw = ((t & 3) ^ ((t >> 3) & 3)) << 3;   // shorts
  const unsigned short* zsrc = zb + (((size_t)m0 + (t >> 2)) << 8) + jsw;
  const unsigned short* esrc = eb + (((size_t)n0 + (t >> 2)) << 8) + jsw;

  // read-side lane constants (byte offsets): row*64 + (kg ^ ((r16>>1)&3))*16
  const int jx = (kg ^ ((r16 >> 1) & 3)) << 4;
  const int arow = ((w << 6) + r16) << 6;   // (w*64 + mi*16 + r16)*64 bytes
  const int brow = r16 << 6;

  // prologue: stage kt=0 into buf 0 (A: 4 loads, B: 2 loads per thread)
  #pragma unroll
  for (int i = 0; i < 4; ++i)
    GL2LDS16(zsrc + (i << 14), (char*)As[0] + (i << 12) + (t << 4));
  #pragma unroll
  for (int i = 0; i < 2; ++i)
    GL2LDS16(esrc + (i << 14), (char*)Bs[0] + (i << 12) + (t << 4));
  __syncthreads();

  #pragma unroll
  for (int kt = 0; kt < 8; ++kt) {
    const int cur = kt & 1;
    if (kt < 7) {                              // issue next-tile stage FIRST (overlap)
      const int ko = (kt + 1) << 5;            // shorts
      #pragma unroll
      for (int i = 0; i < 4; ++i)
        GL2LDS16(zsrc + (i << 14) + ko, (char*)As[cur ^ 1] + (i << 12) + (t << 4));
      #pragma unroll
      for (int i = 0; i < 2; ++i)
        GL2LDS16(esrc + (i << 14) + ko, (char*)Bs[cur ^ 1] + (i << 12) + (t << 4));
    }
    bf16x8 af[4], bq[8];
    #pragma unroll
    for (int mi = 0; mi < 4; ++mi)
      af[mi] = *(const bf16x8*)((const char*)As[cur] + arow + (mi << 10) + jx);
    #pragma unroll
    for (int ni = 0; ni < 8; ++ni)
      bq[ni] = *(const bf16x8*)((const char*)Bs[cur] + brow + (ni << 10) + jx);
    #pragma unroll
    for (int mi = 0; mi < 4; ++mi)
      #pragma unroll
      for (int ni = 0; ni < 8; ++ni)
        acc[mi][ni] = __builtin_amdgcn_mfma_f32_16x16x32_bf16(bq[ni], af[mi], acc[mi][ni], 0, 0, 0);
    __syncthreads();   // drains this kt's stage loads; buf[cur^1] ready; readers done with buf[cur]
  }

  // epilogue: lane's z-row (per mi) = w*64 + mi*16 + r16;
  // code within this block's 128-tile = ni*16 + kg*4 + reg; tile = blockIdx.y
  const u32 kgr = (u32)(kg << 2);
  #pragma unroll
  for (int mi = 0; mi < 4; ++mi) {
    float a1 = 0.f, a2 = 0.f;
    #pragma unroll
    for (int ni = 0; ni < 8; ++ni) {
      #pragma unroll
      for (int reg = 0; reg < 4; ++reg) {
        u32 e = __float_as_uint(acc[mi][ni][reg] + 2.0f);
        float k = __uint_as_float((e & 0xFFFFFF80u) | ((u32)(ni << 4) | kgr | (u32)reg));
        float na2 = __builtin_amdgcn_fmed3f(a1, a2, k);
        a1 = fmaxf(a1, k);
        a2 = na2;
      }
    }
    #pragma unroll
    for (int off = 16; off < 64; off <<= 1) {
      float b1 = __shfl_xor(a1, off, 64);
      float b2 = __shfl_xor(a2, off, 64);
      a2 = fmaxf(fminf(a1, b1), fmaxf(a2, b2));
      a1 = fmaxf(a1, b1);
    }
    if (kg == 0) {
      int row = m0 + (w << 6) + (mi << 4) + r16;
      tt2[((size_t)blockIdx.y << 14) + row] =
          make_uint2(__float_as_uint(a1), __float_as_uint(a2));
    }
  }
}

// ---------------- K2: exact fp32 refinement + index/histogram + out/loss (fused) ------------
__global__ __launch_bounds__(256) void refine_out_kernel(
    const float* __restrict__ z, const float* __restrict__ E,
    const float* __restrict__ zsq, const float* __restrict__ enorm,
    const uint2* __restrict__ tt2, u64* __restrict__ packed,
    float* __restrict__ out, float* __restrict__ out_idx,
    u32* __restrict__ counts, float* __restrict__ loss_acc) {
  __shared__ uint2 tc[64][33];     // [tile][row-in-block], +pad
  __shared__ float zrow[32][260];  // [pixel][channel]; overwritten with out values
  __shared__ float red[4];
  const int t = threadIdx.x, w = t >> 6, lane = t & 63;
  const int m0 = blockIdx.x << 5;  // 512 blocks, 32 rows each (same b)
  const int b = m0 >> 10, p0 = m0 & 1023;

  #pragma unroll
  for (int i = 0; i < 8; ++i) {
    int tau = (i << 3) + (t >> 5);
    tc[tau][t & 31] = tt2[((size_t)tau << 14) + m0 + (t & 31)];
  }
  #pragma unroll
  for (int i = 0; i < 8; ++i) {
    int c = (i << 5) + (t >> 3);
    int p4 = (t & 7) << 2;
    float4 v = *(const float4*)&z[((size_t)b << 18) + ((size_t)c << 10) + p0 + p4];
    zrow[p4 + 0][c] = v.x;
    zrow[p4 + 1][c] = v.y;
    zrow[p4 + 2][c] = v.z;
    zrow[p4 + 3][c] = v.w;
  }
  __syncthreads();

  float wloss = 0.f;
  for (int j = 0; j < 8; ++j) {
    const int rr = (w << 3) + j;
    const int m = m0 + rr;
    uint2 c = tc[lane][rr];                       // lane <-> 128-wide tile
    float f0 = __uint_as_float(c.x), f1 = __uint_as_float(c.y);  // f0 >= f1
    float fm = f0;
    #pragma unroll
    for (int off = 1; off < 64; off <<= 1) fm = fmaxf(fm, __shfl_xor(fm, off, 64));
    float thr = fm - 1.5e-4f;                     // margin on (dot+2) scale
    const float4 zr4 = *(const float4*)&zrow[rr][lane << 2];
    float zsqm = zsq[m];
    u64 best = ~0ull;
    float4 be4 = {0.f, 0.f, 0.f, 0.f};
    #pragma unroll
    for (int s = 0; s < 2; ++s) {
      u32 ck = s ? c.y : c.x;
      float fv = s ? f1 : f0;
      u64 mask = __ballot(fv >= thr);
      while (mask) {
        int src = __ffsll((unsigned long long)mask) - 1;
        mask &= mask - 1;
        u32 key = (u32)__shfl((int)ck, src, 64);
        int idx = (src << 7) | (int)(key & 127u);
        const float4 e4 = *(const float4*)&E[(size_t)idx * CDIM + (lane << 2)];
        float pa = zr4.x * e4.x;                  // identical chain to prior rounds
        pa = fmaf(zr4.y, e4.y, pa);
        pa = fmaf(zr4.z, e4.z, pa);
        pa = fmaf(zr4.w, e4.w, pa);
        #pragma unroll
        for (int off = 1; off < 64; off <<= 1) pa += __shfl_xor(pa, off, 64);
        float ttv = zsqm + enorm[idx];
        float d = ttv - 2.0f * pa;                // exact reference rounding profile
        u64 k2 = ((u64)__float_as_uint(d) << 32) | (u32)idx;
        bool better = k2 < best;                  // wave-uniform
        best = better ? k2 : best;
        be4 = better ? e4 : be4;
      }
    }
    // out = z + (e - z), loss += (e - z)^2; overwrite zrow[rr] with out values
    float4 df, o4;
    df.x = be4.x - zr4.x; df.y = be4.y - zr4.y; df.z = be4.z - zr4.z; df.w = be4.w - zr4.w;
    o4.x = zr4.x + df.x;  o4.y = zr4.y + df.y;  o4.z = zr4.z + df.z;  o4.w = zr4.w + df.w;
    wloss = fmaf(df.x, df.x, wloss);
    wloss = fmaf(df.y, df.y, wloss);
    wloss = fmaf(df.z, df.z, wloss);
    wloss = fmaf(df.w, df.w, wloss);
    *(float4*)&zrow[rr][lane << 2] = o4;
    if (lane == 0) {
      packed[m] = best;
      int idx = (int)(u32)(best & 0xffffffffull);
      out_idx[m] = (float)idx;
      atomicAdd(&counts[idx], 1u);
    }
  }
  #pragma unroll
  for (int off = 32; off; off >>= 1) wloss += __shfl_down(wloss, off, 64);
  if (lane == 0) red[w] = wloss;
  __syncthreads();                                // also guards zrow out-values
  if (t == 0) atomicAdd(loss_acc, red[0] + red[1] + red[2] + red[3]);

  // write out NCHW coalesced (128B per channel segment)
  #pragma unroll
  for (int i = 0; i < 8; ++i) {
    int c = (i << 5) + (t >> 3);
    int p4 = (t & 7) << 2;
    float4 o = { zrow[p4 + 0][c], zrow[p4 + 1][c], zrow[p4 + 2][c], zrow[p4 + 3][c] };
    *(float4*)&out[((size_t)b << 18) + ((size_t)c << 10) + p0 + p4] = o;
  }
}

// ---------------- fallback exact fp32 path ----------------
__global__ void enorm_kernel(const float* __restrict__ E, float* __restrict__ enorm) {
  int wave = threadIdx.x >> 6;
  int lane = threadIdx.x & 63;
  int n = blockIdx.x * 4 + wave;
  float4 v = reinterpret_cast<const float4*>(E + (size_t)n * CDIM)[lane];
  float s = v.x * v.x + v.y * v.y + v.z * v.z + v.w * v.w;
  #pragma unroll
  for (int off = 32; off; off >>= 1) s += __shfl_down(s, off, 64);
  if (lane == 0) enorm[n] = s;
}

__global__ void zsq_kernel(const float* __restrict__ z, float* __restrict__ zsq) {
  int blk = blockIdx.x;
  int j = threadIdx.x;
  int b = blk >> 2;
  int p = ((blk & 3) << 8) + j;
  const float* zp = z + (size_t)b * (CDIM * 1024) + p;
  float acc = 0.f;
  #pragma unroll 8
  for (int c = 0; c < CDIM; ++c) {
    float v = zp[(size_t)c * 1024];
    acc += v * v;
  }
  zsq[(blk << 8) + j] = acc;
}

#define BM 128
#define BN 128
#define BK 32
__global__ __launch_bounds__(256, 2) void dist_kernel(
    const float* __restrict__ z, const float* __restrict__ E,
    const float* __restrict__ zsq, const float* __restrict__ enorm,
    unsigned long long* __restrict__ packed) {
  __shared__ float zs[BK][BM];
  __shared__ float es[BK][BN];
  const int t = threadIdx.x;
  const int m0 = blockIdx.x * BM;
  const int n0 = blockIdx.y * BN;
  const int b = m0 >> 10;
  const int p0 = m0 & 1023;
  const int zc = t >> 5;
  const int zm = (t & 31) << 2;
  const float* zbase = z + (size_t)b * 262144 + p0 + zm;
  const int en = t & 127;
  const int ec = (t >> 7) << 4;
  const float* ebase = E + (size_t)(n0 + en) * CDIM + ec;
  float4 zr[4], er[4];
  #pragma unroll
  for (int r = 0; r < 4; ++r)
    zr[r] = *(const float4*)(zbase + (size_t)(r * 8 + zc) * 1024);
  #pragma unroll
  for (int i = 0; i < 4; ++i)
    er[i] = *(const float4*)(ebase + 4 * i);
  float acc[8][8];
  #pragma unroll
  for (int a = 0; a < 8; ++a)
    #pragma unroll
    for (int bb = 0; bb < 8; ++bb) acc[a][bb] = 0.f;
  const int tx = t & 15, ty = t >> 4;
  for (int kt = 0; kt < CDIM / BK; ++kt) {
    __syncthreads();
    #pragma unroll
    for (int r = 0; r < 4; ++r)
      *(float4*)&zs[r * 8 + zc][zm] = zr[r];
    #pragma unroll
    for (int i = 0; i < 4; ++i) {
      es[ec + 4 * i + 0][en] = er[i].x;
      es[ec + 4 * i + 1][en] = er[i].y;
      es[ec + 4 * i + 2][en] = er[i].z;
      es[ec + 4 * i + 3][en] = er[i].w;
    }
    __syncthreads();
    if (kt + 1 < CDIM / BK) {
      const int c0 = (kt + 1) * BK;
      #pragma unroll
      for (int r = 0; r < 4; ++r)
        zr[r] = *(const float4*)(zbase + (size_t)(c0 + r * 8 + zc) * 1024);
      #pragma unroll
      for (int i = 0; i < 4; ++i)
        er[i] = *(const float4*)(ebase + c0 + 4 * i);
    }
    #pragma unroll 8
    for (int kk = 0; kk < BK; ++kk) {
      float4 za = *(const float4*)&zs[kk][ty * 4];
      float4 zb4 = *(const float4*)&zs[kk][64 + ty * 4];
      float4 ea = *(const float4*)&es[kk][tx * 4];
      float4 eb4 = *(const float4*)&es[kk][64 + tx * 4];
      float zv[8] = {za.x, za.y, za.z, za.w, zb4.x, zb4.y, zb4.z, zb4.w};
      float ev[8] = {ea.x, ea.y, ea.z, ea.w, eb4.x, eb4.y, eb4.z, eb4.w};
      #pragma unroll
      for (int a = 0; a < 8; ++a)
        #pragma unroll
        for (int bb = 0; bb < 8; ++bb)
          acc[a][bb] += zv[a] * ev[bb];
    }
  }
  #pragma unroll
  for (int a = 0; a < 8; ++a) {
    int rloc = (a < 4) ? (ty * 4 + a) : (64 + ty * 4 + (a - 4));
    float zq = zsq[m0 + rloc];
    float bestd = 3.4e38f;
    int bestn = 0;
    #pragma unroll
    for (int bb = 0; bb < 8; ++bb) {
      int nloc = (bb < 4) ? (tx * 4 + bb) : (64 + tx * 4 + (bb - 4));
      int n = n0 + nloc;
      float ttv = zq + enorm[n];
      float d = ttv - 2.0f * acc[a][bb];
      if (d < bestd) { bestd = d; bestn = n; }
    }
    unsigned long long pk =
        ((unsigned long long)__float_as_uint(bestd) << 32) | (unsigned)bestn;
    #pragma unroll
    for (int off = 1; off < 16; off <<= 1) {
      unsigned long long other = __shfl_xor(pk, off, 16);
      if (other < pk) pk = other;
    }
    if (tx == 0) atomicMin(&packed[m0 + rloc], pk);
  }
}

__global__ void idx_kernel(const unsigned long long* __restrict__ packed,
                           float* __restrict__ out_idx, unsigned int* __restrict__ counts) {
  int m = blockIdx.x * 256 + threadIdx.x;
  int idx = (int)(unsigned)(packed[m] & 0xffffffffull);
  out_idx[m] = (float)idx;
  atomicAdd(&counts[idx], 1u);
}

__global__ __launch_bounds__(256) void out_kernel(
    const float* __restrict__ z, const float* __restrict__ E,
    const u64* __restrict__ packed,
    float* __restrict__ out, float* __restrict__ loss_acc) {
  __shared__ float es[32][257];
  const int t = threadIdx.x, w = t >> 6, lane = t & 63;
  const int m0 = blockIdx.x << 5;
  const int b = m0 >> 10, p0 = m0 & 1023;
  #pragma unroll
  for (int i = 0; i < 8; ++i) {
    int pl = (w << 3) + i;
    int idx = (int)(u32)(packed[m0 + pl] & 0xffffffffull);
    float4 v = *(const float4*)&E[((size_t)idx << 8) + (lane << 2)];
    es[pl][(lane << 2) + 0] = v.x;
    es[pl][(lane << 2) + 1] = v.y;
    es[pl][(lane << 2) + 2] = v.z;
    es[pl][(lane << 2) + 3] = v.w;
  }
  __syncthreads();
  const int pp = lane & 31, chi = lane >> 5;
  const size_t gbase = ((size_t)b << 18) + p0 + pp;
  float s = 0.f;
  #pragma unroll 8
  for (int i = 0; i < 32; ++i) {
    int c = (i << 3) + (w << 1) + chi;
    float zv = z[gbase + ((size_t)c << 10)];
    float e = es[pp][c];
    float diff = e - zv;
    out[gbase + ((size_t)c << 10)] = zv + diff;
    s = fmaf(diff, diff, s);
  }
  #pragma unroll
  for (int off = 32; off; off >>= 1) s += __shfl_down(s, off, 64);
  __shared__ float red[4];
  if (lane == 0) red[w] = s;
  __syncthreads();
  if (t == 0) atomicAdd(loss_acc, red[0] + red[1] + red[2] + red[3]);
}

__global__ void scalar_kernel(const unsigned int* __restrict__ counts,
                              const float* __restrict__ loss_acc,
                              float* __restrict__ out) {
  float s = 0.f;
  for (int i = threadIdx.x; i < NCODES; i += 256) {
    float pl = (float)counts[i] * (1.0f / 16384.0f);
    s += pl * logf(pl + 1e-10f);
  }
  #pragma unroll
  for (int off = 32; off; off >>= 1) s += __shfl_down(s, off, 64);
  __shared__ float red[4];
  int wv = threadIdx.x >> 6, lane = threadIdx.x & 63;
  if (lane == 0) red[wv] = s;
  __syncthreads();
  if (threadIdx.x == 0) {
    float tot = red[0] + red[1] + red[2] + red[3];
    out[OUT_ELEMS + MTOT] = (1.0f + BETA) * loss_acc[0] * (1.0f / (float)OUT_ELEMS);
    out[OUT_ELEMS + MTOT + 1] = expf(-tot);
  }
}

extern "C" void kernel_launch(void* const* d_in, const int* in_sizes, int n_in,
                              void* d_out, int out_size, void* d_ws, size_t ws_size,
                              hipStream_t stream) {
  const float* z = (const float*)d_in[0];
  const float* E = (const float*)d_in[1];
  float* out = (float*)d_out;
  char* ws = (char*)d_ws;
  u64* packed = (u64*)(ws + WS_PACKED);
  float* enorm = (float*)(ws + WS_ENORM);
  float* zsq = (float*)(ws + WS_ZSQ);
  u32* counts = (u32*)(ws + WS_COUNTS);
  float* loss_acc = (float*)(ws + WS_LOSS);

  hipMemsetAsync(counts, 0, 32768 + 256, stream);  // counts + loss_acc

  if (ws_size >= WS_NEEDED) {
    unsigned short* zb = (unsigned short*)(ws + WS_ZB);
    unsigned short* ebuf = (unsigned short*)(ws + WS_EB);
    uint2* tt2 = (uint2*)(ws + WS_TT2);
    float* zsq4 = (float*)(ws + WS_ZSQ4);
    conv_kernel<<<2048, 256, 0, stream>>>(z, E, zb, ebuf, zsq4, enorm);
    zsqfin_kernel<<<64, 256, 0, stream>>>(zsq4, zsq);
    dim3 g(MTOT / 256, NCODES / 128);
    gemm_kernel<<<g, 256, 0, stream>>>(zb, ebuf, tt2);
    refine_out_kernel<<<MTOT / 32, 256, 0, stream>>>(z, E, zsq, enorm, tt2, packed,
                                                     out, out + OUT_ELEMS, counts, loss_acc);
  } else {
    hipMemsetAsync(packed, 0xFF, MTOT * 8, stream);
    enorm_kernel<<<NCODES / 4, 256, 0, stream>>>(E, enorm);
    zsq_kernel<<<64, 256, 0, stream>>>(z, zsq);
    dim3 g(MTOT / BM, NCODES / BN);
    dist_kernel<<<g, 256, 0, stream>>>(z, E, zsq, enorm, packed);
    idx_kernel<<<MTOT / 256, 256, 0, stream>>>(packed, out + OUT_ELEMS, counts);
    out_kernel<<<MTOT / 32, 256, 0, stream>>>(z, E, packed, out, loss_acc);
  }

  scalar_kernel<<<1, 256, 0, stream>>>(counts, loss_acc, out);
}

// Round 11
// 141.477 us; speedup vs baseline: 1.6291x; 1.6291x over previous
//
#include <hip/hip_runtime.h>
#include <stdint.h>

typedef unsigned long long u64;
typedef unsigned int u32;

#define CDIM 256
#define NCODES 8192
#define MTOT 16384
#define OUT_ELEMS 4194304   // 16*256*32*32
#define BETA 0.25f

// ws layout (bytes)
#define WS_PACKED 0u            // 16384*8 = 131072
#define WS_ENORM  131072u       // 32768
#define WS_ZSQ    163840u       // 65536
#define WS_COUNTS 229376u       // 32768
#define WS_LOSS   262144u       // 256 (only 4 used)
#define WS_ZSQ4   262400u       // 16384*4*4 = 262144
#define WS_ZB     524544u       // 16384*256*2 = 8388608
#define WS_EB     8913152u      // 8192*256*2 = 4194304
#define WS_TT2    13107456u     // 64*16384*8 = 8388608 (uint2 keys, [tile][m])
#define WS_NEEDED 21496064u

typedef short bf16x8 __attribute__((ext_vector_type(8)));
typedef float f32x4 __attribute__((ext_vector_type(4)));

#define GL2LDS16(g, l) __builtin_amdgcn_global_load_lds(            \
    (const __attribute__((address_space(1))) void*)(g),             \
    (__attribute__((address_space(3))) void*)(l), 16, 0, 0)

__device__ __forceinline__ unsigned short f2bf(float f) {
  u32 u = __float_as_uint(f);
  u32 r = (u + 0x7FFFu + ((u >> 16) & 1u)) >> 16;   // RNE
  return (unsigned short)r;
}

// ---------------- convert: z NCHW->NHWC bf16 + zsq quarters; E->bf16 + enorm ----------------
__global__ void conv_kernel(const float* __restrict__ z, const float* __restrict__ E,
                            unsigned short* __restrict__ zb, unsigned short* __restrict__ eb,
                            float* __restrict__ zsq4, float* __restrict__ enorm) {
  int blk = blockIdx.x;
  int t = threadIdx.x, w = t >> 6, lane = t & 63;
  if (blk < 1024) {
    __shared__ unsigned short tz[64][66];
    __shared__ float part[4][64];
    int b = blk >> 6, rem = blk & 63;
    int ct = rem >> 4, pt = rem & 15;
    int c0 = ct << 6, p0 = pt << 6;
    const float* zp = z + ((size_t)b << 18) + ((size_t)c0 << 10) + p0;
    float sq = 0.f;
    #pragma unroll
    for (int i = 0; i < 16; ++i) {
      int cl = w + (i << 2);
      float v = zp[((size_t)cl << 10) + lane];
      sq = fmaf(v, v, sq);
      tz[cl][lane] = f2bf(v);
    }
    part[w][lane] = sq;
    __syncthreads();
    if (w == 0) {
      float s = ((part[0][lane] + part[1][lane]) + part[2][lane]) + part[3][lane];
      zsq4[(((size_t)b << 10) + p0 + lane) * 4 + ct] = s;
    }
    #pragma unroll
    for (int j = 0; j < 16; ++j) {
      int pl = w + (j << 2);
      zb[(((size_t)b << 10) + p0 + pl) * 256 + c0 + lane] = tz[lane][pl];
    }
  } else {
    int e4 = blk - 1024;                 // 1024 blocks, 8 E-rows each
    size_t base = ((size_t)e4 << 11) + ((size_t)t << 3);
    float4 v0 = *(const float4*)&E[base];
    float4 v1 = *(const float4*)&E[base + 4];
    ushort4 o0 = { f2bf(v0.x), f2bf(v0.y), f2bf(v0.z), f2bf(v0.w) };
    ushort4 o1 = { f2bf(v1.x), f2bf(v1.y), f2bf(v1.z), f2bf(v1.w) };
    *(ushort4*)&eb[base] = o0;
    *(ushort4*)&eb[base + 4] = o1;
    // enorm (order-insensitive: always rounds away against zsq)
    float s = v0.x * v0.x + v0.y * v0.y + v0.z * v0.z + v0.w * v0.w
            + v1.x * v1.x + v1.y * v1.y + v1.z * v1.z + v1.w * v1.w;
    #pragma unroll
    for (int off = 16; off; off >>= 1) s += __shfl_xor(s, off, 32);
    if ((t & 31) == 0) enorm[(e4 << 3) + (t >> 5)] = s;
  }
}

__global__ void zsqfin_kernel(const float* __restrict__ zsq4, float* __restrict__ zsq) {
  int m = blockIdx.x * 256 + threadIdx.x;
  float4 v = *(const float4*)&zsq4[(size_t)m * 4];
  zsq[m] = ((v.x + v.y) + v.z) + v.w;   // ((q0+q1)+q2)+q3, same as passing rounds
}

// ---------------- K1: bf16 MFMA GEMM, r5 geometry (BM=256,BN=128, 256 thr, 4 waves)
// + BK=32 double-buffer T3-minimum 2-phase (stage kt+1 issued BEFORE compute kt).
// launch_bounds(256,2): do NOT over-constrain the allocator (r10: (256,3) forced
// VGPR=84 -> acc spilled to scratch -> 680 MB HBM traffic, 2.4x regression).
// 48 KB LDS still admits 3 blocks/CU at VGPR=128. ----------
__global__ __launch_bounds__(256, 2) void gemm_kernel(
    const unsigned short* __restrict__ zb, const unsigned short* __restrict__ eb,
    uint2* __restrict__ tt2) {
  __shared__ unsigned short As[2][256 * 32];   // 2 x 16 KB
  __shared__ unsigned short Bs[2][128 * 32];   // 2 x 8 KB   (48 KB total)
  const int t = threadIdx.x;
  const int w = t >> 6, lane = t & 63;
  const int r16 = lane & 15, kg = lane >> 4;
  const int m0 = blockIdx.x << 8, n0 = blockIdx.y << 7;

  f32x4 acc[4][8];
  #pragma unroll
  for (int i = 0; i < 4; ++i)
    #pragma unroll
    for (int j = 0; j < 8; ++j) acc[i][j] = (f32x4)0.f;

  // staging: thread t stages granule g=i*256+t -> (row=g>>2, slot=g&3);
  // source granule j = (t&3) ^ ((t>>3)&3)   [= slot ^ ((row>>1)&3)]
  const int jsw = ((t & 3) ^ ((t >> 3) & 3)) << 3;   // shorts
  const unsigned short* zsrc = zb + (((size_t)m0 + (t >> 2)) << 8) + jsw;
  const unsigned short* esrc = eb + (((size_t)n0 + (t >> 2)) << 8) + jsw;

  // read-side lane constants (byte offsets): row*64 + (kg ^ ((r16>>1)&3))*16
  const int jx = (kg ^ ((r16 >> 1) & 3)) << 4;
  const int arow = ((w << 6) + r16) << 6;   // (w*64 + mi*16 + r16)*64 bytes
  const int brow = r16 << 6;

  // prologue: stage kt=0 into buf 0 (A: 4 loads, B: 2 loads per thread)
  #pragma unroll
  for (int i = 0; i < 4; ++i)
    GL2LDS16(zsrc + (i << 14), (char*)As[0] + (i << 12) + (t << 4));
  #pragma unroll
  for (int i = 0; i < 2; ++i)
    GL2LDS16(esrc + (i << 14), (char*)Bs[0] + (i << 12) + (t << 4));
  __syncthreads();

  #pragma unroll
  for (int kt = 0; kt < 8; ++kt) {
    const int cur = kt & 1;
    if (kt < 7) {                              // issue next-tile stage FIRST (overlap)
      const int ko = (kt + 1) << 5;            // shorts
      #pragma unroll
      for (int i = 0; i < 4; ++i)
        GL2LDS16(zsrc + (i << 14) + ko, (char*)As[cur ^ 1] + (i << 12) + (t << 4));
      #pragma unroll
      for (int i = 0; i < 2; ++i)
        GL2LDS16(esrc + (i << 14) + ko, (char*)Bs[cur ^ 1] + (i << 12) + (t << 4));
    }
    bf16x8 af[4], bq[8];
    #pragma unroll
    for (int mi = 0; mi < 4; ++mi)
      af[mi] = *(const bf16x8*)((const char*)As[cur] + arow + (mi << 10) + jx);
    #pragma unroll
    for (int ni = 0; ni < 8; ++ni)
      bq[ni] = *(const bf16x8*)((const char*)Bs[cur] + brow + (ni << 10) + jx);
    #pragma unroll
    for (int mi = 0; mi < 4; ++mi)
      #pragma unroll
      for (int ni = 0; ni < 8; ++ni)
        acc[mi][ni] = __builtin_amdgcn_mfma_f32_16x16x32_bf16(bq[ni], af[mi], acc[mi][ni], 0, 0, 0);
    __syncthreads();   // drains this kt's stage loads; buf[cur^1] ready; readers done with buf[cur]
  }

  // epilogue: lane's z-row (per mi) = w*64 + mi*16 + r16;
  // code within this block's 128-tile = ni*16 + kg*4 + reg; tile = blockIdx.y
  const u32 kgr = (u32)(kg << 2);
  #pragma unroll
  for (int mi = 0; mi < 4; ++mi) {
    float a1 = 0.f, a2 = 0.f;
    #pragma unroll
    for (int ni = 0; ni < 8; ++ni) {
      #pragma unroll
      for (int reg = 0; reg < 4; ++reg) {
        u32 e = __float_as_uint(acc[mi][ni][reg] + 2.0f);
        float k = __uint_as_float((e & 0xFFFFFF80u) | ((u32)(ni << 4) | kgr | (u32)reg));
        float na2 = __builtin_amdgcn_fmed3f(a1, a2, k);
        a1 = fmaxf(a1, k);
        a2 = na2;
      }
    }
    #pragma unroll
    for (int off = 16; off < 64; off <<= 1) {
      float b1 = __shfl_xor(a1, off, 64);
      float b2 = __shfl_xor(a2, off, 64);
      a2 = fmaxf(fminf(a1, b1), fmaxf(a2, b2));
      a1 = fmaxf(a1, b1);
    }
    if (kg == 0) {
      int row = m0 + (w << 6) + (mi << 4) + r16;
      tt2[((size_t)blockIdx.y << 14) + row] =
          make_uint2(__float_as_uint(a1), __float_as_uint(a2));
    }
  }
}

// ---------------- K2: exact fp32 refinement + index/histogram + out/loss (fused) ------------
__global__ __launch_bounds__(256) void refine_out_kernel(
    const float* __restrict__ z, const float* __restrict__ E,
    const float* __restrict__ zsq, const float* __restrict__ enorm,
    const uint2* __restrict__ tt2, u64* __restrict__ packed,
    float* __restrict__ out, float* __restrict__ out_idx,
    u32* __restrict__ counts, float* __restrict__ loss_acc) {
  __shared__ uint2 tc[64][33];     // [tile][row-in-block], +pad
  __shared__ float zrow[32][260];  // [pixel][channel]; overwritten with out values
  __shared__ float red[4];
  const int t = threadIdx.x, w = t >> 6, lane = t & 63;
  const int m0 = blockIdx.x << 5;  // 512 blocks, 32 rows each (same b)
  const int b = m0 >> 10, p0 = m0 & 1023;

  #pragma unroll
  for (int i = 0; i < 8; ++i) {
    int tau = (i << 3) + (t >> 5);
    tc[tau][t & 31] = tt2[((size_t)tau << 14) + m0 + (t & 31)];
  }
  #pragma unroll
  for (int i = 0; i < 8; ++i) {
    int c = (i << 5) + (t >> 3);
    int p4 = (t & 7) << 2;
    float4 v = *(const float4*)&z[((size_t)b << 18) + ((size_t)c << 10) + p0 + p4];
    zrow[p4 + 0][c] = v.x;
    zrow[p4 + 1][c] = v.y;
    zrow[p4 + 2][c] = v.z;
    zrow[p4 + 3][c] = v.w;
  }
  __syncthreads();

  float wloss = 0.f;
  for (int j = 0; j < 8; ++j) {
    const int rr = (w << 3) + j;
    const int m = m0 + rr;
    uint2 c = tc[lane][rr];                       // lane <-> 128-wide tile
    float f0 = __uint_as_float(c.x), f1 = __uint_as_float(c.y);  // f0 >= f1
    float fm = f0;
    #pragma unroll
    for (int off = 1; off < 64; off <<= 1) fm = fmaxf(fm, __shfl_xor(fm, off, 64));
    float thr = fm - 1.5e-4f;                     // margin on (dot+2) scale
    const float4 zr4 = *(const float4*)&zrow[rr][lane << 2];
    float zsqm = zsq[m];
    u64 best = ~0ull;
    float4 be4 = {0.f, 0.f, 0.f, 0.f};
    #pragma unroll
    for (int s = 0; s < 2; ++s) {
      u32 ck = s ? c.y : c.x;
      float fv = s ? f1 : f0;
      u64 mask = __ballot(fv >= thr);
      while (mask) {
        int src = __ffsll((unsigned long long)mask) - 1;
        mask &= mask - 1;
        u32 key = (u32)__shfl((int)ck, src, 64);
        int idx = (src << 7) | (int)(key & 127u);
        const float4 e4 = *(const float4*)&E[(size_t)idx * CDIM + (lane << 2)];
        float pa = zr4.x * e4.x;                  // identical chain to prior rounds
        pa = fmaf(zr4.y, e4.y, pa);
        pa = fmaf(zr4.z, e4.z, pa);
        pa = fmaf(zr4.w, e4.w, pa);
        #pragma unroll
        for (int off = 1; off < 64; off <<= 1) pa += __shfl_xor(pa, off, 64);
        float ttv = zsqm + enorm[idx];
        float d = ttv - 2.0f * pa;                // exact reference rounding profile
        u64 k2 = ((u64)__float_as_uint(d) << 32) | (u32)idx;
        bool better = k2 < best;                  // wave-uniform
        best = better ? k2 : best;
        be4 = better ? e4 : be4;
      }
    }
    // out = z + (e - z), loss += (e - z)^2; overwrite zrow[rr] with out values
    float4 df, o4;
    df.x = be4.x - zr4.x; df.y = be4.y - zr4.y; df.z = be4.z - zr4.z; df.w = be4.w - zr4.w;
    o4.x = zr4.x + df.x;  o4.y = zr4.y + df.y;  o4.z = zr4.z + df.z;  o4.w = zr4.w + df.w;
    wloss = fmaf(df.x, df.x, wloss);
    wloss = fmaf(df.y, df.y, wloss);
    wloss = fmaf(df.z, df.z, wloss);
    wloss = fmaf(df.w, df.w, wloss);
    *(float4*)&zrow[rr][lane << 2] = o4;
    if (lane == 0) {
      packed[m] = best;
      int idx = (int)(u32)(best & 0xffffffffull);
      out_idx[m] = (float)idx;
      atomicAdd(&counts[idx], 1u);
    }
  }
  #pragma unroll
  for (int off = 32; off; off >>= 1) wloss += __shfl_down(wloss, off, 64);
  if (lane == 0) red[w] = wloss;
  __syncthreads();                                // also guards zrow out-values
  if (t == 0) atomicAdd(loss_acc, red[0] + red[1] + red[2] + red[3]);

  // write out NCHW coalesced (128B per channel segment)
  #pragma unroll
  for (int i = 0; i < 8; ++i) {
    int c = (i << 5) + (t >> 3);
    int p4 = (t & 7) << 2;
    float4 o = { zrow[p4 + 0][c], zrow[p4 + 1][c], zrow[p4 + 2][c], zrow[p4 + 3][c] };
    *(float4*)&out[((size_t)b << 18) + ((size_t)c << 10) + p0 + p4] = o;
  }
}

// ---------------- fallback exact fp32 path ----------------
__global__ void enorm_kernel(const float* __restrict__ E, float* __restrict__ enorm) {
  int wave = threadIdx.x >> 6;
  int lane = threadIdx.x & 63;
  int n = blockIdx.x * 4 + wave;
  float4 v = reinterpret_cast<const float4*>(E + (size_t)n * CDIM)[lane];
  float s = v.x * v.x + v.y * v.y + v.z * v.z + v.w * v.w;
  #pragma unroll
  for (int off = 32; off; off >>= 1) s += __shfl_down(s, off, 64);
  if (lane == 0) enorm[n] = s;
}

__global__ void zsq_kernel(const float* __restrict__ z, float* __restrict__ zsq) {
  int blk = blockIdx.x;
  int j = threadIdx.x;
  int b = blk >> 2;
  int p = ((blk & 3) << 8) + j;
  const float* zp = z + (size_t)b * (CDIM * 1024) + p;
  float acc = 0.f;
  #pragma unroll 8
  for (int c = 0; c < CDIM; ++c) {
    float v = zp[(size_t)c * 1024];
    acc += v * v;
  }
  zsq[(blk << 8) + j] = acc;
}

#define BM 128
#define BN 128
#define BK 32
__global__ __launch_bounds__(256, 2) void dist_kernel(
    const float* __restrict__ z, const float* __restrict__ E,
    const float* __restrict__ zsq, const float* __restrict__ enorm,
    unsigned long long* __restrict__ packed) {
  __shared__ float zs[BK][BM];
  __shared__ float es[BK][BN];
  const int t = threadIdx.x;
  const int m0 = blockIdx.x * BM;
  const int n0 = blockIdx.y * BN;
  const int b = m0 >> 10;
  const int p0 = m0 & 1023;
  const int zc = t >> 5;
  const int zm = (t & 31) << 2;
  const float* zbase = z + (size_t)b * 262144 + p0 + zm;
  const int en = t & 127;
  const int ec = (t >> 7) << 4;
  const float* ebase = E + (size_t)(n0 + en) * CDIM + ec;
  float4 zr[4], er[4];
  #pragma unroll
  for (int r = 0; r < 4; ++r)
    zr[r] = *(const float4*)(zbase + (size_t)(r * 8 + zc) * 1024);
  #pragma unroll
  for (int i = 0; i < 4; ++i)
    er[i] = *(const float4*)(ebase + 4 * i);
  float acc[8][8];
  #pragma unroll
  for (int a = 0; a < 8; ++a)
    #pragma unroll
    for (int bb = 0; bb < 8; ++bb) acc[a][bb] = 0.f;
  const int tx = t & 15, ty = t >> 4;
  for (int kt = 0; kt < CDIM / BK; ++kt) {
    __syncthreads();
    #pragma unroll
    for (int r = 0; r < 4; ++r)
      *(float4*)&zs[r * 8 + zc][zm] = zr[r];
    #pragma unroll
    for (int i = 0; i < 4; ++i) {
      es[ec + 4 * i + 0][en] = er[i].x;
      es[ec + 4 * i + 1][en] = er[i].y;
      es[ec + 4 * i + 2][en] = er[i].z;
      es[ec + 4 * i + 3][en] = er[i].w;
    }
    __syncthreads();
    if (kt + 1 < CDIM / BK) {
      const int c0 = (kt + 1) * BK;
      #pragma unroll
      for (int r = 0; r < 4; ++r)
        zr[r] = *(const float4*)(zbase + (size_t)(c0 + r * 8 + zc) * 1024);
      #pragma unroll
      for (int i = 0; i < 4; ++i)
        er[i] = *(const float4*)(ebase + c0 + 4 * i);
    }
    #pragma unroll 8
    for (int kk = 0; kk < BK; ++kk) {
      float4 za = *(const float4*)&zs[kk][ty * 4];
      float4 zb4 = *(const float4*)&zs[kk][64 + ty * 4];
      float4 ea = *(const float4*)&es[kk][tx * 4];
      float4 eb4 = *(const float4*)&es[kk][64 + tx * 4];
      float zv[8] = {za.x, za.y, za.z, za.w, zb4.x, zb4.y, zb4.z, zb4.w};
      float ev[8] = {ea.x, ea.y, ea.z, ea.w, eb4.x, eb4.y, eb4.z, eb4.w};
      #pragma unroll
      for (int a = 0; a < 8; ++a)
        #pragma unroll
        for (int bb = 0; bb < 8; ++bb)
          acc[a][bb] += zv[a] * ev[bb];
    }
  }
  #pragma unroll
  for (int a = 0; a < 8; ++a) {
    int rloc = (a < 4) ? (ty * 4 + a) : (64 + ty * 4 + (a - 4));
    float zq = zsq[m0 + rloc];
    float bestd = 3.4e38f;
    int bestn = 0;
    #pragma unroll
    for (int bb = 0; bb < 8; ++bb) {
      int nloc = (bb < 4) ? (tx * 4 + bb) : (64 + tx * 4 + (bb - 4));
      int n = n0 + nloc;
      float ttv = zq + enorm[n];
      float d = ttv - 2.0f * acc[a][bb];
      if (d < bestd) { bestd = d; bestn = n; }
    }
    unsigned long long pk =
        ((unsigned long long)__float_as_uint(bestd) << 32) | (unsigned)bestn;
    #pragma unroll
    for (int off = 1; off < 16; off <<= 1) {
      unsigned long long other = __shfl_xor(pk, off, 16);
      if (other < pk) pk = other;
    }
    if (tx == 0) atomicMin(&packed[m0 + rloc], pk);
  }
}

__global__ void idx_kernel(const unsigned long long* __restrict__ packed,
                           float* __restrict__ out_idx, unsigned int* __restrict__ counts) {
  int m = blockIdx.x * 256 + threadIdx.x;
  int idx = (int)(unsigned)(packed[m] & 0xffffffffull);
  out_idx[m] = (float)idx;
  atomicAdd(&counts[idx], 1u);
}

__global__ __launch_bounds__(256) void out_kernel(
    const float* __restrict__ z, const float* __restrict__ E,
    const u64* __restrict__ packed,
    float* __restrict__ out, float* __restrict__ loss_acc) {
  __shared__ float es[32][257];
  const int t = threadIdx.x, w = t >> 6, lane = t & 63;
  const int m0 = blockIdx.x << 5;
  const int b = m0 >> 10, p0 = m0 & 1023;
  #pragma unroll
  for (int i = 0; i < 8; ++i) {
    int pl = (w << 3) + i;
    int idx = (int)(u32)(packed[m0 + pl] & 0xffffffffull);
    float4 v = *(const float4*)&E[((size_t)idx << 8) + (lane << 2)];
    es[pl][(lane << 2) + 0] = v.x;
    es[pl][(lane << 2) + 1] = v.y;
    es[pl][(lane << 2) + 2] = v.z;
    es[pl][(lane << 2) + 3] = v.w;
  }
  __syncthreads();
  const int pp = lane & 31, chi = lane >> 5;
  const size_t gbase = ((size_t)b << 18) + p0 + pp;
  float s = 0.f;
  #pragma unroll 8
  for (int i = 0; i < 32; ++i) {
    int c = (i << 3) + (w << 1) + chi;
    float zv = z[gbase + ((size_t)c << 10)];
    float e = es[pp][c];
    float diff = e - zv;
    out[gbase + ((size_t)c << 10)] = zv + diff;
    s = fmaf(diff, diff, s);
  }
  #pragma unroll
  for (int off = 32; off; off >>= 1) s += __shfl_down(s, off, 64);
  __shared__ float red[4];
  if (lane == 0) red[w] = s;
  __syncthreads();
  if (t == 0) atomicAdd(loss_acc, red[0] + red[1] + red[2] + red[3]);
}

__global__ void scalar_kernel(const unsigned int* __restrict__ counts,
                              const float* __restrict__ loss_acc,
                              float* __restrict__ out) {
  float s = 0.f;
  for (int i = threadIdx.x; i < NCODES; i += 256) {
    float pl = (float)counts[i] * (1.0f / 16384.0f);
    s += pl * logf(pl + 1e-10f);
  }
  #pragma unroll
  for (int off = 32; off; off >>= 1) s += __shfl_down(s, off, 64);
  __shared__ float red[4];
  int wv = threadIdx.x >> 6, lane = threadIdx.x & 63;
  if (lane == 0) red[wv] = s;
  __syncthreads();
  if (threadIdx.x == 0) {
    float tot = red[0] + red[1] + red[2] + red[3];
    out[OUT_ELEMS + MTOT] = (1.0f + BETA) * loss_acc[0] * (1.0f / (float)OUT_ELEMS);
    out[OUT_ELEMS + MTOT + 1] = expf(-tot);
  }
}

extern "C" void kernel_launch(void* const* d_in, const int* in_sizes, int n_in,
                              void* d_out, int out_size, void* d_ws, size_t ws_size,
                              hipStream_t stream) {
  const float* z = (const float*)d_in[0];
  const float* E = (const float*)d_in[1];
  float* out = (float*)d_out;
  char* ws = (char*)d_ws;
  u64* packed = (u64*)(ws + WS_PACKED);
  float* enorm = (float*)(ws + WS_ENORM);
  float* zsq = (float*)(ws + WS_ZSQ);
  u32* counts = (u32*)(ws + WS_COUNTS);
  float* loss_acc = (float*)(ws + WS_LOSS);

  hipMemsetAsync(counts, 0, 32768 + 256, stream);  // counts + loss_acc

  if (ws_size >= WS_NEEDED) {
    unsigned short* zb = (unsigned short*)(ws + WS_ZB);
    unsigned short* ebuf = (unsigned short*)(ws + WS_EB);
    uint2* tt2 = (uint2*)(ws + WS_TT2);
    float* zsq4 = (float*)(ws + WS_ZSQ4);
    conv_kernel<<<2048, 256, 0, stream>>>(z, E, zb, ebuf, zsq4, enorm);
    zsqfin_kernel<<<64, 256, 0, stream>>>(zsq4, zsq);
    dim3 g(MTOT / 256, NCODES / 128);
    gemm_kernel<<<g, 256, 0, stream>>>(zb, ebuf, tt2);
    refine_out_kernel<<<MTOT / 32, 256, 0, stream>>>(z, E, zsq, enorm, tt2, packed,
                                                     out, out + OUT_ELEMS, counts, loss_acc);
  } else {
    hipMemsetAsync(packed, 0xFF, MTOT * 8, stream);
    enorm_kernel<<<NCODES / 4, 256, 0, stream>>>(E, enorm);
    zsq_kernel<<<64, 256, 0, stream>>>(z, zsq);
    dim3 g(MTOT / BM, NCODES / BN);
    dist_kernel<<<g, 256, 0, stream>>>(z, E, zsq, enorm, packed);
    idx_kernel<<<MTOT / 256, 256, 0, stream>>>(packed, out + OUT_ELEMS, counts);
    out_kernel<<<MTOT / 32, 256, 0, stream>>>(z, E, packed, out, loss_acc);
  }

  scalar_kernel<<<1, 256, 0, stream>>>(counts, loss_acc, out);
}

// Round 12
// 132.230 us; speedup vs baseline: 1.7430x; 1.0699x over previous
//
#include <hip/hip_runtime.h>
#include <stdint.h>

typedef unsigned long long u64;
typedef unsigned int u32;

#define CDIM 256
#define NCODES 8192
#define MTOT 16384
#define OUT_ELEMS 4194304   // 16*256*32*32
#define BETA 0.25f

// ws layout (bytes)
#define WS_PACKED 0u            // 16384*8 = 131072
#define WS_ENORM  131072u       // 32768
#define WS_ZSQ    163840u       // 65536
#define WS_COUNTS 229376u       // 32768
#define WS_LOSS   262144u       // 256 (only 4 used)
#define WS_ZSQ4   262400u       // 16384*4*4 = 262144
#define WS_ZB     524544u       // 16384*256*2 = 8388608
#define WS_EB     8913152u      // 8192*256*2 = 4194304
#define WS_TT2    13107456u     // 64*16384*8 = 8388608 (uint2 keys, [tile][m])
#define WS_NEEDED 21496064u

typedef short bf16x8 __attribute__((ext_vector_type(8)));
typedef float f32x4 __attribute__((ext_vector_type(4)));

#define GL2LDS16(g, l) __builtin_amdgcn_global_load_lds(            \
    (const __attribute__((address_space(1))) void*)(g),             \
    (__attribute__((address_space(3))) void*)(l), 16, 0, 0)

__device__ __forceinline__ unsigned short f2bf(float f) {
  u32 u = __float_as_uint(f);
  u32 r = (u + 0x7FFFu + ((u >> 16) & 1u)) >> 16;   // RNE
  return (unsigned short)r;
}

// ---------------- convert: z NCHW->NHWC bf16 + zsq quarters; E->bf16 + enorm ----------------
__global__ void conv_kernel(const float* __restrict__ z, const float* __restrict__ E,
                            unsigned short* __restrict__ zb, unsigned short* __restrict__ eb,
                            float* __restrict__ zsq4, float* __restrict__ enorm) {
  int blk = blockIdx.x;
  int t = threadIdx.x, w = t >> 6, lane = t & 63;
  if (blk < 1024) {
    __shared__ unsigned short tz[64][66];
    __shared__ float part[4][64];
    int b = blk >> 6, rem = blk & 63;
    int ct = rem >> 4, pt = rem & 15;
    int c0 = ct << 6, p0 = pt << 6;
    const float* zp = z + ((size_t)b << 18) + ((size_t)c0 << 10) + p0;
    float sq = 0.f;
    #pragma unroll
    for (int i = 0; i < 16; ++i) {
      int cl = w + (i << 2);
      float v = zp[((size_t)cl << 10) + lane];
      sq = fmaf(v, v, sq);
      tz[cl][lane] = f2bf(v);
    }
    part[w][lane] = sq;
    __syncthreads();
    if (w == 0) {
      float s = ((part[0][lane] + part[1][lane]) + part[2][lane]) + part[3][lane];
      zsq4[(((size_t)b << 10) + p0 + lane) * 4 + ct] = s;
    }
    #pragma unroll
    for (int j = 0; j < 16; ++j) {
      int pl = w + (j << 2);
      zb[(((size_t)b << 10) + p0 + pl) * 256 + c0 + lane] = tz[lane][pl];
    }
  } else {
    int e4 = blk - 1024;                 // 1024 blocks, 8 E-rows each
    size_t base = ((size_t)e4 << 11) + ((size_t)t << 3);
    float4 v0 = *(const float4*)&E[base];
    float4 v1 = *(const float4*)&E[base + 4];
    ushort4 o0 = { f2bf(v0.x), f2bf(v0.y), f2bf(v0.z), f2bf(v0.w) };
    ushort4 o1 = { f2bf(v1.x), f2bf(v1.y), f2bf(v1.z), f2bf(v1.w) };
    *(ushort4*)&eb[base] = o0;
    *(ushort4*)&eb[base + 4] = o1;
    // enorm (order-insensitive: always rounds away against zsq)
    float s = v0.x * v0.x + v0.y * v0.y + v0.z * v0.z + v0.w * v0.w
            + v1.x * v1.x + v1.y * v1.y + v1.z * v1.z + v1.w * v1.w;
    #pragma unroll
    for (int off = 16; off; off >>= 1) s += __shfl_xor(s, off, 32);
    if ((t & 31) == 0) enorm[(e4 << 3) + (t >> 5)] = s;
  }
}

// ---------------- K1: bf16 MFMA GEMM — round-5 kernel verbatim (best measured: 81.5 us,
// MfmaUtil 36.4%, bank-conflicts 0). BM=256,BN=128,BK=64, 256 thr / 4 waves,
// single-buffer 2-barrier loop, XOR-swizzled LDS, swapped operands (lane owns rows).
// Keys: as_float((as_uint(dot+2) & ~127) | col), fmed3 in-lane top-2. ----------
__global__ __launch_bounds__(256, 2) void gemm_kernel(
    const unsigned short* __restrict__ zb, const unsigned short* __restrict__ eb,
    uint2* __restrict__ tt2) {
  __shared__ unsigned short As[256 * 64];   // 32 KB, row = 8 granules of 16B
  __shared__ unsigned short Bs[128 * 64];   // 16 KB
  const int t = threadIdx.x;
  const int w = t >> 6, lane = t & 63;
  const int r16 = lane & 15, kg = lane >> 4;
  const int m0 = blockIdx.x << 8, n0 = blockIdx.y << 7;

  f32x4 acc[4][8];
  #pragma unroll
  for (int i = 0; i < 4; ++i)
    #pragma unroll
    for (int j = 0; j < 8; ++j) acc[i][j] = (f32x4)0.f;

  // staging: thread t stages granule g=i*256+t -> (row=g>>3, stored j'=g&7),
  // source granule j = j' ^ (row&7)  (inverse-swizzled global source)
  const int jsw = ((t & 7) ^ ((t >> 3) & 7)) << 3;   // shorts
  const unsigned short* zsrc = zb + (((size_t)m0 + (t >> 3)) << 8) + jsw;
  const unsigned short* esrc = eb + (((size_t)n0 + (t >> 3)) << 8) + jsw;

  // read-side lane constants (byte offsets); row&7 == r16&7 for all fragments
  const int jx0 = ((kg ^ (r16 & 7)) << 4);
  const int jx1 = (((4 + kg) ^ (r16 & 7)) << 4);
  const int arow = ((w << 6) + r16) << 7;   // (w*64+r16)*128 bytes
  const int brow = r16 << 7;

  for (int kt = 0; kt < 4; ++kt) {
    if (kt) __syncthreads();
    const int ko = kt << 6;   // shorts
    #pragma unroll
    for (int i = 0; i < 8; ++i)
      GL2LDS16(zsrc + (i << 13) + ko, (char*)As + (i << 12) + (t << 4));
    #pragma unroll
    for (int i = 0; i < 4; ++i)
      GL2LDS16(esrc + (i << 13) + ko, (char*)Bs + (i << 12) + (t << 4));
    __syncthreads();
    #pragma unroll
    for (int s = 0; s < 2; ++s) {
      const int jx = s ? jx1 : jx0;
      bf16x8 af[4], bq[8];
      #pragma unroll
      for (int mi = 0; mi < 4; ++mi)
        af[mi] = *(const bf16x8*)((const char*)As + arow + (mi << 11) + jx);
      #pragma unroll
      for (int ni = 0; ni < 8; ++ni)
        bq[ni] = *(const bf16x8*)((const char*)Bs + brow + (ni << 11) + jx);
      #pragma unroll
      for (int mi = 0; mi < 4; ++mi)
        #pragma unroll
        for (int ni = 0; ni < 8; ++ni)
          acc[mi][ni] = __builtin_amdgcn_mfma_f32_16x16x32_bf16(bq[ni], af[mi], acc[mi][ni], 0, 0, 0);
    }
  }

  // epilogue: lane's z-row (per mi) = w*64 + mi*16 + r16;
  // code within this block's 128-tile = ni*16 + kg*4 + reg; tile = blockIdx.y
  const u32 kgr = (u32)(kg << 2);
  #pragma unroll
  for (int mi = 0; mi < 4; ++mi) {
    float a1 = 0.f, a2 = 0.f;
    #pragma unroll
    for (int ni = 0; ni < 8; ++ni) {
      #pragma unroll
      for (int reg = 0; reg < 4; ++reg) {
        u32 e = __float_as_uint(acc[mi][ni][reg] + 2.0f);
        float k = __uint_as_float((e & 0xFFFFFF80u) | ((u32)(ni << 4) | kgr | (u32)reg));
        float na2 = __builtin_amdgcn_fmed3f(a1, a2, k);
        a1 = fmaxf(a1, k);
        a2 = na2;
      }
    }
    #pragma unroll
    for (int off = 16; off < 64; off <<= 1) {
      float b1 = __shfl_xor(a1, off, 64);
      float b2 = __shfl_xor(a2, off, 64);
      a2 = fmaxf(fminf(a1, b1), fmaxf(a2, b2));
      a1 = fmaxf(a1, b1);
    }
    if (kg == 0) {
      int row = m0 + (w << 6) + (mi << 4) + r16;
      tt2[((size_t)blockIdx.y << 14) + row] =
          make_uint2(__float_as_uint(a1), __float_as_uint(a2));
    }
  }
}

// ---------------- K2: exact fp32 refinement + index/histogram + out/loss (fused) ------------
__global__ __launch_bounds__(256) void refine_out_kernel(
    const float* __restrict__ z, const float* __restrict__ E,
    const float* __restrict__ zsq4, const float* __restrict__ enorm,
    const uint2* __restrict__ tt2, u64* __restrict__ packed,
    float* __restrict__ out, float* __restrict__ out_idx,
    u32* __restrict__ counts, float* __restrict__ loss_acc) {
  __shared__ uint2 tc[64][33];     // [tile][row-in-block], +pad
  __shared__ float zrow[32][260];  // [pixel][channel]; overwritten with out values
  __shared__ float red[4];
  const int t = threadIdx.x, w = t >> 6, lane = t & 63;
  const int m0 = blockIdx.x << 5;  // 512 blocks, 32 rows each (same b)
  const int b = m0 >> 10, p0 = m0 & 1023;

  #pragma unroll
  for (int i = 0; i < 8; ++i) {
    int tau = (i << 3) + (t >> 5);
    tc[tau][t & 31] = tt2[((size_t)tau << 14) + m0 + (t & 31)];
  }
  #pragma unroll
  for (int i = 0; i < 8; ++i) {
    int c = (i << 5) + (t >> 3);
    int p4 = (t & 7) << 2;
    float4 v = *(const float4*)&z[((size_t)b << 18) + ((size_t)c << 10) + p0 + p4];
    zrow[p4 + 0][c] = v.x;
    zrow[p4 + 1][c] = v.y;
    zrow[p4 + 2][c] = v.z;
    zrow[p4 + 3][c] = v.w;
  }
  __syncthreads();

  float wloss = 0.f;
  for (int j = 0; j < 8; ++j) {
    const int rr = (w << 3) + j;
    const int m = m0 + rr;
    uint2 c = tc[lane][rr];                       // lane <-> 128-wide tile
    float f0 = __uint_as_float(c.x), f1 = __uint_as_float(c.y);  // f0 >= f1
    float fm = f0;
    #pragma unroll
    for (int off = 1; off < 64; off <<= 1) fm = fmaxf(fm, __shfl_xor(fm, off, 64));
    float thr = fm - 1.5e-4f;                     // margin on (dot+2) scale
    const float4 zr4 = *(const float4*)&zrow[rr][lane << 2];
    // zsq = ((q0+q1)+q2)+q3 — identical tree to the former zsqfin kernel
    const float4 q4 = *(const float4*)&zsq4[(size_t)m * 4];
    float zsqm = ((q4.x + q4.y) + q4.z) + q4.w;
    u64 best = ~0ull;
    float4 be4 = {0.f, 0.f, 0.f, 0.f};
    #pragma unroll
    for (int s = 0; s < 2; ++s) {
      u32 ck = s ? c.y : c.x;
      float fv = s ? f1 : f0;
      u64 mask = __ballot(fv >= thr);
      while (mask) {
        int src = __ffsll((unsigned long long)mask) - 1;
        mask &= mask - 1;
        u32 key = (u32)__shfl((int)ck, src, 64);
        int idx = (src << 7) | (int)(key & 127u);
        const float4 e4 = *(const float4*)&E[(size_t)idx * CDIM + (lane << 2)];
        float pa = zr4.x * e4.x;                  // identical chain to prior rounds
        pa = fmaf(zr4.y, e4.y, pa);
        pa = fmaf(zr4.z, e4.z, pa);
        pa = fmaf(zr4.w, e4.w, pa);
        #pragma unroll
        for (int off = 1; off < 64; off <<= 1) pa += __shfl_xor(pa, off, 64);
        float ttv = zsqm + enorm[idx];
        float d = ttv - 2.0f * pa;                // exact reference rounding profile
        u64 k2 = ((u64)__float_as_uint(d) << 32) | (u32)idx;
        bool better = k2 < best;                  // wave-uniform
        best = better ? k2 : best;
        be4 = better ? e4 : be4;
      }
    }
    // out = z + (e - z), loss += (e - z)^2; overwrite zrow[rr] with out values
    float4 df, o4;
    df.x = be4.x - zr4.x; df.y = be4.y - zr4.y; df.z = be4.z - zr4.z; df.w = be4.w - zr4.w;
    o4.x = zr4.x + df.x;  o4.y = zr4.y + df.y;  o4.z = zr4.z + df.z;  o4.w = zr4.w + df.w;
    wloss = fmaf(df.x, df.x, wloss);
    wloss = fmaf(df.y, df.y, wloss);
    wloss = fmaf(df.z, df.z, wloss);
    wloss = fmaf(df.w, df.w, wloss);
    *(float4*)&zrow[rr][lane << 2] = o4;
    if (lane == 0) {
      packed[m] = best;
      int idx = (int)(u32)(best & 0xffffffffull);
      out_idx[m] = (float)idx;
      atomicAdd(&counts[idx], 1u);
    }
  }
  #pragma unroll
  for (int off = 32; off; off >>= 1) wloss += __shfl_down(wloss, off, 64);
  if (lane == 0) red[w] = wloss;
  __syncthreads();                                // also guards zrow out-values
  if (t == 0) atomicAdd(loss_acc, red[0] + red[1] + red[2] + red[3]);

  // write out NCHW coalesced (128B per channel segment)
  #pragma unroll
  for (int i = 0; i < 8; ++i) {
    int c = (i << 5) + (t >> 3);
    int p4 = (t & 7) << 2;
    float4 o = { zrow[p4 + 0][c], zrow[p4 + 1][c], zrow[p4 + 2][c], zrow[p4 + 3][c] };
    *(float4*)&out[((size_t)b << 18) + ((size_t)c << 10) + p0 + p4] = o;
  }
}

// ---------------- fallback exact fp32 path ----------------
__global__ void enorm_kernel(const float* __restrict__ E, float* __restrict__ enorm) {
  int wave = threadIdx.x >> 6;
  int lane = threadIdx.x & 63;
  int n = blockIdx.x * 4 + wave;
  float4 v = reinterpret_cast<const float4*>(E + (size_t)n * CDIM)[lane];
  float s = v.x * v.x + v.y * v.y + v.z * v.z + v.w * v.w;
  #pragma unroll
  for (int off = 32; off; off >>= 1) s += __shfl_down(s, off, 64);
  if (lane == 0) enorm[n] = s;
}

__global__ void zsq_kernel(const float* __restrict__ z, float* __restrict__ zsq) {
  int blk = blockIdx.x;
  int j = threadIdx.x;
  int b = blk >> 2;
  int p = ((blk & 3) << 8) + j;
  const float* zp = z + (size_t)b * (CDIM * 1024) + p;
  float acc = 0.f;
  #pragma unroll 8
  for (int c = 0; c < CDIM; ++c) {
    float v = zp[(size_t)c * 1024];
    acc += v * v;
  }
  zsq[(blk << 8) + j] = acc;
}

#define BM 128
#define BN 128
#define BK 32
__global__ __launch_bounds__(256, 2) void dist_kernel(
    const float* __restrict__ z, const float* __restrict__ E,
    const float* __restrict__ zsq, const float* __restrict__ enorm,
    unsigned long long* __restrict__ packed) {
  __shared__ float zs[BK][BM];
  __shared__ float es[BK][BN];
  const int t = threadIdx.x;
  const int m0 = blockIdx.x * BM;
  const int n0 = blockIdx.y * BN;
  const int b = m0 >> 10;
  const int p0 = m0 & 1023;
  const int zc = t >> 5;
  const int zm = (t & 31) << 2;
  const float* zbase = z + (size_t)b * 262144 + p0 + zm;
  const int en = t & 127;
  const int ec = (t >> 7) << 4;
  const float* ebase = E + (size_t)(n0 + en) * CDIM + ec;
  float4 zr[4], er[4];
  #pragma unroll
  for (int r = 0; r < 4; ++r)
    zr[r] = *(const float4*)(zbase + (size_t)(r * 8 + zc) * 1024);
  #pragma unroll
  for (int i = 0; i < 4; ++i)
    er[i] = *(const float4*)(ebase + 4 * i);
  float acc[8][8];
  #pragma unroll
  for (int a = 0; a < 8; ++a)
    #pragma unroll
    for (int bb = 0; bb < 8; ++bb) acc[a][bb] = 0.f;
  const int tx = t & 15, ty = t >> 4;
  for (int kt = 0; kt < CDIM / BK; ++kt) {
    __syncthreads();
    #pragma unroll
    for (int r = 0; r < 4; ++r)
      *(float4*)&zs[r * 8 + zc][zm] = zr[r];
    #pragma unroll
    for (int i = 0; i < 4; ++i) {
      es[ec + 4 * i + 0][en] = er[i].x;
      es[ec + 4 * i + 1][en] = er[i].y;
      es[ec + 4 * i + 2][en] = er[i].z;
      es[ec + 4 * i + 3][en] = er[i].w;
    }
    __syncthreads();
    if (kt + 1 < CDIM / BK) {
      const int c0 = (kt + 1) * BK;
      #pragma unroll
      for (int r = 0; r < 4; ++r)
        zr[r] = *(const float4*)(zbase + (size_t)(c0 + r * 8 + zc) * 1024);
      #pragma unroll
      for (int i = 0; i < 4; ++i)
        er[i] = *(const float4*)(ebase + c0 + 4 * i);
    }
    #pragma unroll 8
    for (int kk = 0; kk < BK; ++kk) {
      float4 za = *(const float4*)&zs[kk][ty * 4];
      float4 zb4 = *(const float4*)&zs[kk][64 + ty * 4];
      float4 ea = *(const float4*)&es[kk][tx * 4];
      float4 eb4 = *(const float4*)&es[kk][64 + tx * 4];
      float zv[8] = {za.x, za.y, za.z, za.w, zb4.x, zb4.y, zb4.z, zb4.w};
      float ev[8] = {ea.x, ea.y, ea.z, ea.w, eb4.x, eb4.y, eb4.z, eb4.w};
      #pragma unroll
      for (int a = 0; a < 8; ++a)
        #pragma unroll
        for (int bb = 0; bb < 8; ++bb)
          acc[a][bb] += zv[a] * ev[bb];
    }
  }
  #pragma unroll
  for (int a = 0; a < 8; ++a) {
    int rloc = (a < 4) ? (ty * 4 + a) : (64 + ty * 4 + (a - 4));
    float zq = zsq[m0 + rloc];
    float bestd = 3.4e38f;
    int bestn = 0;
    #pragma unroll
    for (int bb = 0; bb < 8; ++bb) {
      int nloc = (bb < 4) ? (tx * 4 + bb) : (64 + tx * 4 + (bb - 4));
      int n = n0 + nloc;
      float ttv = zq + enorm[n];
      float d = ttv - 2.0f * acc[a][bb];
      if (d < bestd) { bestd = d; bestn = n; }
    }
    unsigned long long pk =
        ((unsigned long long)__float_as_uint(bestd) << 32) | (unsigned)bestn;
    #pragma unroll
    for (int off = 1; off < 16; off <<= 1) {
      unsigned long long other = __shfl_xor(pk, off, 16);
      if (other < pk) pk = other;
    }
    if (tx == 0) atomicMin(&packed[m0 + rloc], pk);
  }
}

__global__ void idx_kernel(const unsigned long long* __restrict__ packed,
                           float* __restrict__ out_idx, unsigned int* __restrict__ counts) {
  int m = blockIdx.x * 256 + threadIdx.x;
  int idx = (int)(unsigned)(packed[m] & 0xffffffffull);
  out_idx[m] = (float)idx;
  atomicAdd(&counts[idx], 1u);
}

__global__ __launch_bounds__(256) void out_kernel(
    const float* __restrict__ z, const float* __restrict__ E,
    const u64* __restrict__ packed,
    float* __restrict__ out, float* __restrict__ loss_acc) {
  __shared__ float es[32][257];
  const int t = threadIdx.x, w = t >> 6, lane = t & 63;
  const int m0 = blockIdx.x << 5;
  const int b = m0 >> 10, p0 = m0 & 1023;
  #pragma unroll
  for (int i = 0; i < 8; ++i) {
    int pl = (w << 3) + i;
    int idx = (int)(u32)(packed[m0 + pl] & 0xffffffffull);
    float4 v = *(const float4*)&E[((size_t)idx << 8) + (lane << 2)];
    es[pl][(lane << 2) + 0] = v.x;
    es[pl][(lane << 2) + 1] = v.y;
    es[pl][(lane << 2) + 2] = v.z;
    es[pl][(lane << 2) + 3] = v.w;
  }
  __syncthreads();
  const int pp = lane & 31, chi = lane >> 5;
  const size_t gbase = ((size_t)b << 18) + p0 + pp;
  float s = 0.f;
  #pragma unroll 8
  for (int i = 0; i < 32; ++i) {
    int c = (i << 3) + (w << 1) + chi;
    float zv = z[gbase + ((size_t)c << 10)];
    float e = es[pp][c];
    float diff = e - zv;
    out[gbase + ((size_t)c << 10)] = zv + diff;
    s = fmaf(diff, diff, s);
  }
  #pragma unroll
  for (int off = 32; off; off >>= 1) s += __shfl_down(s, off, 64);
  __shared__ float red[4];
  if (lane == 0) red[w] = s;
  __syncthreads();
  if (t == 0) atomicAdd(loss_acc, red[0] + red[1] + red[2] + red[3]);
}

__global__ void scalar_kernel(const unsigned int* __restrict__ counts,
                              const float* __restrict__ loss_acc,
                              float* __restrict__ out) {
  float s = 0.f;
  for (int i = threadIdx.x; i < NCODES; i += 256) {
    float pl = (float)counts[i] * (1.0f / 16384.0f);
    s += pl * logf(pl + 1e-10f);
  }
  #pragma unroll
  for (int off = 32; off; off >>= 1) s += __shfl_down(s, off, 64);
  __shared__ float red[4];
  int wv = threadIdx.x >> 6, lane = threadIdx.x & 63;
  if (lane == 0) red[wv] = s;
  __syncthreads();
  if (threadIdx.x == 0) {
    float tot = red[0] + red[1] + red[2] + red[3];
    out[OUT_ELEMS + MTOT] = (1.0f + BETA) * loss_acc[0] * (1.0f / (float)OUT_ELEMS);
    out[OUT_ELEMS + MTOT + 1] = expf(-tot);
  }
}

extern "C" void kernel_launch(void* const* d_in, const int* in_sizes, int n_in,
                              void* d_out, int out_size, void* d_ws, size_t ws_size,
                              hipStream_t stream) {
  const float* z = (const float*)d_in[0];
  const float* E = (const float*)d_in[1];
  float* out = (float*)d_out;
  char* ws = (char*)d_ws;
  u64* packed = (u64*)(ws + WS_PACKED);
  float* enorm = (float*)(ws + WS_ENORM);
  float* zsq = (float*)(ws + WS_ZSQ);
  u32* counts = (u32*)(ws + WS_COUNTS);
  float* loss_acc = (float*)(ws + WS_LOSS);

  hipMemsetAsync(counts, 0, 32768 + 256, stream);  // counts + loss_acc

  if (ws_size >= WS_NEEDED) {
    unsigned short* zb = (unsigned short*)(ws + WS_ZB);
    unsigned short* ebuf = (unsigned short*)(ws + WS_EB);
    uint2* tt2 = (uint2*)(ws + WS_TT2);
    float* zsq4 = (float*)(ws + WS_ZSQ4);
    conv_kernel<<<2048, 256, 0, stream>>>(z, E, zb, ebuf, zsq4, enorm);
    dim3 g(MTOT / 256, NCODES / 128);
    gemm_kernel<<<g, 256, 0, stream>>>(zb, ebuf, tt2);
    refine_out_kernel<<<MTOT / 32, 256, 0, stream>>>(z, E, zsq4, enorm, tt2, packed,
                                                     out, out + OUT_ELEMS, counts, loss_acc);
  } else {
    hipMemsetAsync(packed, 0xFF, MTOT * 8, stream);
    enorm_kernel<<<NCODES / 4, 256, 0, stream>>>(E, enorm);
    zsq_kernel<<<64, 256, 0, stream>>>(z, zsq);
    dim3 g(MTOT / BM, NCODES / BN);
    dist_kernel<<<g, 256, 0, stream>>>(z, E, zsq, enorm, packed);
    idx_kernel<<<MTOT / 256, 256, 0, stream>>>(packed, out + OUT_ELEMS, counts);
    out_kernel<<<MTOT / 32, 256, 0, stream>>>(z, E, packed, out, loss_acc);
  }

  scalar_kernel<<<1, 256, 0, stream>>>(counts, loss_acc, out);
}

// Round 13
// 126.918 us; speedup vs baseline: 1.8160x; 1.0419x over previous
//
#include <hip/hip_runtime.h>
#include <stdint.h>

typedef unsigned long long u64;
typedef unsigned int u32;

#define CDIM 256
#define NCODES 8192
#define MTOT 16384
#define OUT_ELEMS 4194304   // 16*256*32*32
#define BETA 0.25f

// ws layout (bytes)
#define WS_PACKED 0u            // 16384*8 = 131072
#define WS_ENORM  131072u       // 32768
#define WS_ZSQ    163840u       // 65536
#define WS_COUNTS 229376u       // 32768
#define WS_LOSS   262144u       // 256 (only 4 used)
#define WS_ZSQ4   262400u       // 16384*4*4 = 262144
#define WS_ZB     524544u       // 16384*256*2 = 8388608
#define WS_EB     8913152u      // 8192*256*2 = 4194304
#define WS_TT2    13107456u     // 64*16384*8 = 8388608 (uint2 keys, [tile][m])
#define WS_NEEDED 21496064u

typedef short bf16x8 __attribute__((ext_vector_type(8)));
typedef float f32x4 __attribute__((ext_vector_type(4)));

#define GL2LDS16(g, l) __builtin_amdgcn_global_load_lds(            \
    (const __attribute__((address_space(1))) void*)(g),             \
    (__attribute__((address_space(3))) void*)(l), 16, 0, 0)

__device__ __forceinline__ unsigned short f2bf(float f) {
  u32 u = __float_as_uint(f);
  u32 r = (u + 0x7FFFu + ((u >> 16) & 1u)) >> 16;   // RNE
  return (unsigned short)r;
}

// ---------------- convert: z NCHW->NHWC bf16 + zsq quarters; E->bf16 + enorm ----------------
// zsq summation tree FROZEN (matches numpy d-grid tie structure): part[w] = seq-16 over
// channels c0+w+4i for fixed pixel, then ((p0+p1)+p2)+p3. Stores vectorized to ushort4.
// E-branch blocks also zero counts/loss (replaces the memset launch; stream-ordered
// before refine_out which is the only consumer).
__global__ void conv_kernel(const float* __restrict__ z, const float* __restrict__ E,
                            unsigned short* __restrict__ zb, unsigned short* __restrict__ eb,
                            float* __restrict__ zsq4, float* __restrict__ enorm,
                            u32* __restrict__ counts, float* __restrict__ loss_acc) {
  int blk = blockIdx.x;
  int t = threadIdx.x, w = t >> 6, lane = t & 63;
  if (blk < 1024) {
    __shared__ unsigned short tz[64][66];
    __shared__ float part[4][64];
    int b = blk >> 6, rem = blk & 63;
    int ct = rem >> 4, pt = rem & 15;
    int c0 = ct << 6, p0 = pt << 6;
    const float* zp = z + ((size_t)b << 18) + ((size_t)c0 << 10) + p0;
    float sq = 0.f;
    #pragma unroll
    for (int i = 0; i < 16; ++i) {
      int cl = w + (i << 2);
      float v = zp[((size_t)cl << 10) + lane];
      sq = fmaf(v, v, sq);
      tz[cl][lane] = f2bf(v);
    }
    part[w][lane] = sq;
    __syncthreads();
    if (w == 0) {
      float s = ((part[0][lane] + part[1][lane]) + part[2][lane]) + part[3][lane];
      zsq4[(((size_t)b << 10) + p0 + lane) * 4 + ct] = s;
    }
    // vectorized zb stores: warp w owns pixels 16w..16w+15; lane -> 4 consecutive channels
    const int cc = (lane & 15) << 2;
    #pragma unroll
    for (int j = 0; j < 4; ++j) {
      int pl = (w << 4) | (j << 2) | (lane >> 4);
      ushort4 o = { tz[cc][pl], tz[cc + 1][pl], tz[cc + 2][pl], tz[cc + 3][pl] };
      *(ushort4*)&zb[(((size_t)b << 10) + p0 + pl) * 256 + c0 + cc] = o;
    }
  } else {
    int e4 = blk - 1024;                 // 1024 blocks, 8 E-rows each
    size_t base = ((size_t)e4 << 11) + ((size_t)t << 3);
    float4 v0 = *(const float4*)&E[base];
    float4 v1 = *(const float4*)&E[base + 4];
    ushort4 o0 = { f2bf(v0.x), f2bf(v0.y), f2bf(v0.z), f2bf(v0.w) };
    ushort4 o1 = { f2bf(v1.x), f2bf(v1.y), f2bf(v1.z), f2bf(v1.w) };
    *(ushort4*)&eb[base] = o0;
    *(ushort4*)&eb[base + 4] = o1;
    // enorm (order-insensitive: always rounds away against zsq)
    float s = v0.x * v0.x + v0.y * v0.y + v0.z * v0.z + v0.w * v0.w
            + v1.x * v1.x + v1.y * v1.y + v1.z * v1.z + v1.w * v1.w;
    #pragma unroll
    for (int off = 16; off; off >>= 1) s += __shfl_xor(s, off, 32);
    if ((t & 31) == 0) enorm[(e4 << 3) + (t >> 5)] = s;
    // fold the counts/loss memset into the first 33 E-blocks (runs before refine_out)
    if (e4 < 32) counts[(e4 << 8) + t] = 0u;
    else if (e4 == 32 && t < 64) ((u32*)loss_acc)[t] = 0u;
  }
}

// ---------------- K1: bf16 MFMA GEMM — round-5 kernel verbatim (best measured: 81.5 us,
// MfmaUtil 36.4%, bank-conflicts 0; 841 TF = documented m97-structure plateau).
// BM=256,BN=128,BK=64, 256 thr / 4 waves, single-buffer 2-barrier loop,
// XOR-swizzled LDS, swapped operands (lane owns rows). ----------
__global__ __launch_bounds__(256, 2) void gemm_kernel(
    const unsigned short* __restrict__ zb, const unsigned short* __restrict__ eb,
    uint2* __restrict__ tt2) {
  __shared__ unsigned short As[256 * 64];   // 32 KB, row = 8 granules of 16B
  __shared__ unsigned short Bs[128 * 64];   // 16 KB
  const int t = threadIdx.x;
  const int w = t >> 6, lane = t & 63;
  const int r16 = lane & 15, kg = lane >> 4;
  const int m0 = blockIdx.x << 8, n0 = blockIdx.y << 7;

  f32x4 acc[4][8];
  #pragma unroll
  for (int i = 0; i < 4; ++i)
    #pragma unroll
    for (int j = 0; j < 8; ++j) acc[i][j] = (f32x4)0.f;

  // staging: thread t stages granule g=i*256+t -> (row=g>>3, stored j'=g&7),
  // source granule j = j' ^ (row&7)  (inverse-swizzled global source)
  const int jsw = ((t & 7) ^ ((t >> 3) & 7)) << 3;   // shorts
  const unsigned short* zsrc = zb + (((size_t)m0 + (t >> 3)) << 8) + jsw;
  const unsigned short* esrc = eb + (((size_t)n0 + (t >> 3)) << 8) + jsw;

  // read-side lane constants (byte offsets); row&7 == r16&7 for all fragments
  const int jx0 = ((kg ^ (r16 & 7)) << 4);
  const int jx1 = (((4 + kg) ^ (r16 & 7)) << 4);
  const int arow = ((w << 6) + r16) << 7;   // (w*64+r16)*128 bytes
  const int brow = r16 << 7;

  for (int kt = 0; kt < 4; ++kt) {
    if (kt) __syncthreads();
    const int ko = kt << 6;   // shorts
    #pragma unroll
    for (int i = 0; i < 8; ++i)
      GL2LDS16(zsrc + (i << 13) + ko, (char*)As + (i << 12) + (t << 4));
    #pragma unroll
    for (int i = 0; i < 4; ++i)
      GL2LDS16(esrc + (i << 13) + ko, (char*)Bs + (i << 12) + (t << 4));
    __syncthreads();
    #pragma unroll
    for (int s = 0; s < 2; ++s) {
      const int jx = s ? jx1 : jx0;
      bf16x8 af[4], bq[8];
      #pragma unroll
      for (int mi = 0; mi < 4; ++mi)
        af[mi] = *(const bf16x8*)((const char*)As + arow + (mi << 11) + jx);
      #pragma unroll
      for (int ni = 0; ni < 8; ++ni)
        bq[ni] = *(const bf16x8*)((const char*)Bs + brow + (ni << 11) + jx);
      #pragma unroll
      for (int mi = 0; mi < 4; ++mi)
        #pragma unroll
        for (int ni = 0; ni < 8; ++ni)
          acc[mi][ni] = __builtin_amdgcn_mfma_f32_16x16x32_bf16(bq[ni], af[mi], acc[mi][ni], 0, 0, 0);
    }
  }

  // epilogue: lane's z-row (per mi) = w*64 + mi*16 + r16;
  // code within this block's 128-tile = ni*16 + kg*4 + reg; tile = blockIdx.y
  const u32 kgr = (u32)(kg << 2);
  #pragma unroll
  for (int mi = 0; mi < 4; ++mi) {
    float a1 = 0.f, a2 = 0.f;
    #pragma unroll
    for (int ni = 0; ni < 8; ++ni) {
      #pragma unroll
      for (int reg = 0; reg < 4; ++reg) {
        u32 e = __float_as_uint(acc[mi][ni][reg] + 2.0f);
        float k = __uint_as_float((e & 0xFFFFFF80u) | ((u32)(ni << 4) | kgr | (u32)reg));
        float na2 = __builtin_amdgcn_fmed3f(a1, a2, k);
        a1 = fmaxf(a1, k);
        a2 = na2;
      }
    }
    #pragma unroll
    for (int off = 16; off < 64; off <<= 1) {
      float b1 = __shfl_xor(a1, off, 64);
      float b2 = __shfl_xor(a2, off, 64);
      a2 = fmaxf(fminf(a1, b1), fmaxf(a2, b2));
      a1 = fmaxf(a1, b1);
    }
    if (kg == 0) {
      int row = m0 + (w << 6) + (mi << 4) + r16;
      tt2[((size_t)blockIdx.y << 14) + row] =
          make_uint2(__float_as_uint(a1), __float_as_uint(a2));
    }
  }
}

// ---------------- K2: exact fp32 refinement + index/histogram + out/loss (fused) ------------
__global__ __launch_bounds__(256) void refine_out_kernel(
    const float* __restrict__ z, const float* __restrict__ E,
    const float* __restrict__ zsq4, const float* __restrict__ enorm,
    const uint2* __restrict__ tt2, u64* __restrict__ packed,
    float* __restrict__ out, float* __restrict__ out_idx,
    u32* __restrict__ counts, float* __restrict__ loss_acc) {
  __shared__ uint2 tc[64][33];     // [tile][row-in-block], +pad
  __shared__ float zrow[32][260];  // [pixel][channel]; overwritten with out values
  __shared__ float red[4];
  const int t = threadIdx.x, w = t >> 6, lane = t & 63;
  const int m0 = blockIdx.x << 5;  // 512 blocks, 32 rows each (same b)
  const int b = m0 >> 10, p0 = m0 & 1023;

  #pragma unroll
  for (int i = 0; i < 8; ++i) {
    int tau = (i << 3) + (t >> 5);
    tc[tau][t & 31] = tt2[((size_t)tau << 14) + m0 + (t & 31)];
  }
  #pragma unroll
  for (int i = 0; i < 8; ++i) {
    int c = (i << 5) + (t >> 3);
    int p4 = (t & 7) << 2;
    float4 v = *(const float4*)&z[((size_t)b << 18) + ((size_t)c << 10) + p0 + p4];
    zrow[p4 + 0][c] = v.x;
    zrow[p4 + 1][c] = v.y;
    zrow[p4 + 2][c] = v.z;
    zrow[p4 + 3][c] = v.w;
  }
  __syncthreads();

  float wloss = 0.f;
  for (int j = 0; j < 8; ++j) {
    const int rr = (w << 3) + j;
    const int m = m0 + rr;
    uint2 c = tc[lane][rr];                       // lane <-> 128-wide tile
    float f0 = __uint_as_float(c.x), f1 = __uint_as_float(c.y);  // f0 >= f1
    float fm = f0;
    #pragma unroll
    for (int off = 1; off < 64; off <<= 1) fm = fmaxf(fm, __shfl_xor(fm, off, 64));
    float thr = fm - 1.5e-4f;                     // margin on (dot+2) scale
    const float4 zr4 = *(const float4*)&zrow[rr][lane << 2];
    // zsq = ((q0+q1)+q2)+q3 — identical tree to prior passing rounds
    const float4 q4 = *(const float4*)&zsq4[(size_t)m * 4];
    float zsqm = ((q4.x + q4.y) + q4.z) + q4.w;
    u64 best = ~0ull;
    float4 be4 = {0.f, 0.f, 0.f, 0.f};
    #pragma unroll
    for (int s = 0; s < 2; ++s) {
      u32 ck = s ? c.y : c.x;
      float fv = s ? f1 : f0;
      u64 mask = __ballot(fv >= thr);
      while (mask) {
        int src = __ffsll((unsigned long long)mask) - 1;
        mask &= mask - 1;
        u32 key = (u32)__shfl((int)ck, src, 64);
        int idx = (src << 7) | (int)(key & 127u);
        const float4 e4 = *(const float4*)&E[(size_t)idx * CDIM + (lane << 2)];
        float pa = zr4.x * e4.x;                  // identical chain to prior rounds
        pa = fmaf(zr4.y, e4.y, pa);
        pa = fmaf(zr4.z, e4.z, pa);
        pa = fmaf(zr4.w, e4.w, pa);
        #pragma unroll
        for (int off = 1; off < 64; off <<= 1) pa += __shfl_xor(pa, off, 64);
        float ttv = zsqm + enorm[idx];
        float d = ttv - 2.0f * pa;                // exact reference rounding profile
        u64 k2 = ((u64)__float_as_uint(d) << 32) | (u32)idx;
        bool better = k2 < best;                  // wave-uniform
        best = better ? k2 : best;
        be4 = better ? e4 : be4;
      }
    }
    // out = z + (e - z), loss += (e - z)^2; overwrite zrow[rr] with out values
    float4 df, o4;
    df.x = be4.x - zr4.x; df.y = be4.y - zr4.y; df.z = be4.z - zr4.z; df.w = be4.w - zr4.w;
    o4.x = zr4.x + df.x;  o4.y = zr4.y + df.y;  o4.z = zr4.z + df.z;  o4.w = zr4.w + df.w;
    wloss = fmaf(df.x, df.x, wloss);
    wloss = fmaf(df.y, df.y, wloss);
    wloss = fmaf(df.z, df.z, wloss);
    wloss = fmaf(df.w, df.w, wloss);
    *(float4*)&zrow[rr][lane << 2] = o4;
    if (lane == 0) {
      packed[m] = best;
      int idx = (int)(u32)(best & 0xffffffffull);
      out_idx[m] = (float)idx;
      atomicAdd(&counts[idx], 1u);
    }
  }
  #pragma unroll
  for (int off = 32; off; off >>= 1) wloss += __shfl_down(wloss, off, 64);
  if (lane == 0) red[w] = wloss;
  __syncthreads();                                // also guards zrow out-values
  if (t == 0) atomicAdd(loss_acc, red[0] + red[1] + red[2] + red[3]);

  // write out NCHW coalesced (128B per channel segment)
  #pragma unroll
  for (int i = 0; i < 8; ++i) {
    int c = (i << 5) + (t >> 3);
    int p4 = (t & 7) << 2;
    float4 o = { zrow[p4 + 0][c], zrow[p4 + 1][c], zrow[p4 + 2][c], zrow[p4 + 3][c] };
    *(float4*)&out[((size_t)b << 18) + ((size_t)c << 10) + p0 + p4] = o;
  }
}

// ---------------- fallback exact fp32 path ----------------
__global__ void enorm_kernel(const float* __restrict__ E, float* __restrict__ enorm) {
  int wave = threadIdx.x >> 6;
  int lane = threadIdx.x & 63;
  int n = blockIdx.x * 4 + wave;
  float4 v = reinterpret_cast<const float4*>(E + (size_t)n * CDIM)[lane];
  float s = v.x * v.x + v.y * v.y + v.z * v.z + v.w * v.w;
  #pragma unroll
  for (int off = 32; off; off >>= 1) s += __shfl_down(s, off, 64);
  if (lane == 0) enorm[n] = s;
}

__global__ void zsq_kernel(const float* __restrict__ z, float* __restrict__ zsq) {
  int blk = blockIdx.x;
  int j = threadIdx.x;
  int b = blk >> 2;
  int p = ((blk & 3) << 8) + j;
  const float* zp = z + (size_t)b * (CDIM * 1024) + p;
  float acc = 0.f;
  #pragma unroll 8
  for (int c = 0; c < CDIM; ++c) {
    float v = zp[(size_t)c * 1024];
    acc += v * v;
  }
  zsq[(blk << 8) + j] = acc;
}

#define BM 128
#define BN 128
#define BK 32
__global__ __launch_bounds__(256, 2) void dist_kernel(
    const float* __restrict__ z, const float* __restrict__ E,
    const float* __restrict__ zsq, const float* __restrict__ enorm,
    unsigned long long* __restrict__ packed) {
  __shared__ float zs[BK][BM];
  __shared__ float es[BK][BN];
  const int t = threadIdx.x;
  const int m0 = blockIdx.x * BM;
  const int n0 = blockIdx.y * BN;
  const int b = m0 >> 10;
  const int p0 = m0 & 1023;
  const int zc = t >> 5;
  const int zm = (t & 31) << 2;
  const float* zbase = z + (size_t)b * 262144 + p0 + zm;
  const int en = t & 127;
  const int ec = (t >> 7) << 4;
  const float* ebase = E + (size_t)(n0 + en) * CDIM + ec;
  float4 zr[4], er[4];
  #pragma unroll
  for (int r = 0; r < 4; ++r)
    zr[r] = *(const float4*)(zbase + (size_t)(r * 8 + zc) * 1024);
  #pragma unroll
  for (int i = 0; i < 4; ++i)
    er[i] = *(const float4*)(ebase + 4 * i);
  float acc[8][8];
  #pragma unroll
  for (int a = 0; a < 8; ++a)
    #pragma unroll
    for (int bb = 0; bb < 8; ++bb) acc[a][bb] = 0.f;
  const int tx = t & 15, ty = t >> 4;
  for (int kt = 0; kt < CDIM / BK; ++kt) {
    __syncthreads();
    #pragma unroll
    for (int r = 0; r < 4; ++r)
      *(float4*)&zs[r * 8 + zc][zm] = zr[r];
    #pragma unroll
    for (int i = 0; i < 4; ++i) {
      es[ec + 4 * i + 0][en] = er[i].x;
      es[ec + 4 * i + 1][en] = er[i].y;
      es[ec + 4 * i + 2][en] = er[i].z;
      es[ec + 4 * i + 3][en] = er[i].w;
    }
    __syncthreads();
    if (kt + 1 < CDIM / BK) {
      const int c0 = (kt + 1) * BK;
      #pragma unroll
      for (int r = 0; r < 4; ++r)
        zr[r] = *(const float4*)(zbase + (size_t)(c0 + r * 8 + zc) * 1024);
      #pragma unroll
      for (int i = 0; i < 4; ++i)
        er[i] = *(const float4*)(ebase + c0 + 4 * i);
    }
    #pragma unroll 8
    for (int kk = 0; kk < BK; ++kk) {
      float4 za = *(const float4*)&zs[kk][ty * 4];
      float4 zb4 = *(const float4*)&zs[kk][64 + ty * 4];
      float4 ea = *(const float4*)&es[kk][tx * 4];
      float4 eb4 = *(const float4*)&es[kk][64 + tx * 4];
      float zv[8] = {za.x, za.y, za.z, za.w, zb4.x, zb4.y, zb4.z, zb4.w};
      float ev[8] = {ea.x, ea.y, ea.z, ea.w, eb4.x, eb4.y, eb4.z, eb4.w};
      #pragma unroll
      for (int a = 0; a < 8; ++a)
        #pragma unroll
        for (int bb = 0; bb < 8; ++bb)
          acc[a][bb] += zv[a] * ev[bb];
    }
  }
  #pragma unroll
  for (int a = 0; a < 8; ++a) {
    int rloc = (a < 4) ? (ty * 4 + a) : (64 + ty * 4 + (a - 4));
    float zq = zsq[m0 + rloc];
    float bestd = 3.4e38f;
    int bestn = 0;
    #pragma unroll
    for (int bb = 0; bb < 8; ++bb) {
      int nloc = (bb < 4) ? (tx * 4 + bb) : (64 + tx * 4 + (bb - 4));
      int n = n0 + nloc;
      float ttv = zq + enorm[n];
      float d = ttv - 2.0f * acc[a][bb];
      if (d < bestd) { bestd = d; bestn = n; }
    }
    unsigned long long pk =
        ((unsigned long long)__float_as_uint(bestd) << 32) | (unsigned)bestn;
    #pragma unroll
    for (int off = 1; off < 16; off <<= 1) {
      unsigned long long other = __shfl_xor(pk, off, 16);
      if (other < pk) pk = other;
    }
    if (tx == 0) atomicMin(&packed[m0 + rloc], pk);
  }
}

__global__ void idx_kernel(const unsigned long long* __restrict__ packed,
                           float* __restrict__ out_idx, unsigned int* __restrict__ counts) {
  int m = blockIdx.x * 256 + threadIdx.x;
  int idx = (int)(unsigned)(packed[m] & 0xffffffffull);
  out_idx[m] = (float)idx;
  atomicAdd(&counts[idx], 1u);
}

__global__ __launch_bounds__(256) void out_kernel(
    const float* __restrict__ z, const float* __restrict__ E,
    const u64* __restrict__ packed,
    float* __restrict__ out, float* __restrict__ loss_acc) {
  __shared__ float es[32][257];
  const int t = threadIdx.x, w = t >> 6, lane = t & 63;
  const int m0 = blockIdx.x << 5;
  const int b = m0 >> 10, p0 = m0 & 1023;
  #pragma unroll
  for (int i = 0; i < 8; ++i) {
    int pl = (w << 3) + i;
    int idx = (int)(u32)(packed[m0 + pl] & 0xffffffffull);
    float4 v = *(const float4*)&E[((size_t)idx << 8) + (lane << 2)];
    es[pl][(lane << 2) + 0] = v.x;
    es[pl][(lane << 2) + 1] = v.y;
    es[pl][(lane << 2) + 2] = v.z;
    es[pl][(lane << 2) + 3] = v.w;
  }
  __syncthreads();
  const int pp = lane & 31, chi = lane >> 5;
  const size_t gbase = ((size_t)b << 18) + p0 + pp;
  float s = 0.f;
  #pragma unroll 8
  for (int i = 0; i < 32; ++i) {
    int c = (i << 3) + (w << 1) + chi;
    float zv = z[gbase + ((size_t)c << 10)];
    float e = es[pp][c];
    float diff = e - zv;
    out[gbase + ((size_t)c << 10)] = zv + diff;
    s = fmaf(diff, diff, s);
  }
  #pragma unroll
  for (int off = 32; off; off >>= 1) s += __shfl_down(s, off, 64);
  __shared__ float red[4];
  if (lane == 0) red[w] = s;
  __syncthreads();
  if (t == 0) atomicAdd(loss_acc, red[0] + red[1] + red[2] + red[3]);
}

__global__ void scalar_kernel(const unsigned int* __restrict__ counts,
                              const float* __restrict__ loss_acc,
                              float* __restrict__ out) {
  float s = 0.f;
  for (int i = threadIdx.x; i < NCODES; i += 256) {
    float pl = (float)counts[i] * (1.0f / 16384.0f);
    s += pl * logf(pl + 1e-10f);
  }
  #pragma unroll
  for (int off = 32; off; off >>= 1) s += __shfl_down(s, off, 64);
  __shared__ float red[4];
  int wv = threadIdx.x >> 6, lane = threadIdx.x & 63;
  if (lane == 0) red[wv] = s;
  __syncthreads();
  if (threadIdx.x == 0) {
    float tot = red[0] + red[1] + red[2] + red[3];
    out[OUT_ELEMS + MTOT] = (1.0f + BETA) * loss_acc[0] * (1.0f / (float)OUT_ELEMS);
    out[OUT_ELEMS + MTOT + 1] = expf(-tot);
  }
}

extern "C" void kernel_launch(void* const* d_in, const int* in_sizes, int n_in,
                              void* d_out, int out_size, void* d_ws, size_t ws_size,
                              hipStream_t stream) {
  const float* z = (const float*)d_in[0];
  const float* E = (const float*)d_in[1];
  float* out = (float*)d_out;
  char* ws = (char*)d_ws;
  u64* packed = (u64*)(ws + WS_PACKED);
  float* enorm = (float*)(ws + WS_ENORM);
  float* zsq = (float*)(ws + WS_ZSQ);
  u32* counts = (u32*)(ws + WS_COUNTS);
  float* loss_acc = (float*)(ws + WS_LOSS);

  if (ws_size >= WS_NEEDED) {
    unsigned short* zb = (unsigned short*)(ws + WS_ZB);
    unsigned short* ebuf = (unsigned short*)(ws + WS_EB);
    uint2* tt2 = (uint2*)(ws + WS_TT2);
    float* zsq4 = (float*)(ws + WS_ZSQ4);
    conv_kernel<<<2048, 256, 0, stream>>>(z, E, zb, ebuf, zsq4, enorm, counts, loss_acc);
    dim3 g(MTOT / 256, NCODES / 128);
    gemm_kernel<<<g, 256, 0, stream>>>(zb, ebuf, tt2);
    refine_out_kernel<<<MTOT / 32, 256, 0, stream>>>(z, E, zsq4, enorm, tt2, packed,
                                                     out, out + OUT_ELEMS, counts, loss_acc);
  } else {
    hipMemsetAsync(counts, 0, 32768 + 256, stream);
    hipMemsetAsync(packed, 0xFF, MTOT * 8, stream);
    enorm_kernel<<<NCODES / 4, 256, 0, stream>>>(E, enorm);
    zsq_kernel<<<64, 256, 0, stream>>>(z, zsq);
    dim3 g(MTOT / BM, NCODES / BN);
    dist_kernel<<<g, 256, 0, stream>>>(z, E, zsq, enorm, packed);
    idx_kernel<<<MTOT / 256, 256, 0, stream>>>(packed, out + OUT_ELEMS, counts);
    out_kernel<<<MTOT / 32, 256, 0, stream>>>(z, E, packed, out, loss_acc);
  }

  scalar_kernel<<<1, 256, 0, stream>>>(counts, loss_acc, out);
}